// Round 7
// baseline (3019.615 us; speedup 1.0000x reference)
//
#include <hip/hip_runtime.h>
#include <cmath>

#define CLIPV 20.0f
#define EPSV 1e-6f

__device__ __forceinline__ float sigmoidf_(float x){ return 1.0f/(1.0f + expf(-x)); }
__device__ __forceinline__ float softplusf_(float x){ return (x > 20.0f) ? x : log1pf(expf(x)); }
__device__ __forceinline__ float clipf_(float x){ return fminf(fmaxf(x, -CLIPV), CLIPV); }

__device__ __forceinline__ float wave_sum64(float v){
  #pragma unroll
  for (int off=32; off>=1; off>>=1) v += __shfl_xor(v, off, 64);
  return v;
}
__device__ __forceinline__ float wave_max64(float v){
  #pragma unroll
  for (int off=32; off>=1; off>>=1) v = fmaxf(v, __shfl_xor(v, off, 64));
  return v;
}
__device__ __forceinline__ float block_sum256(float v, float* s_red){
  v = wave_sum64(v);
  __syncthreads();
  if ((threadIdx.x & 63) == 0) s_red[threadIdx.x>>6] = v;
  __syncthreads();
  return s_red[0]+s_red[1]+s_red[2]+s_red[3];
}
__device__ __forceinline__ float block_max256(float v, float* s_red){
  v = wave_max64(v);
  __syncthreads();
  if ((threadIdx.x & 63) == 0) s_red[threadIdx.x>>6] = v;
  __syncthreads();
  return fmaxf(fmaxf(s_red[0],s_red[1]), fmaxf(s_red[2],s_red[3]));
}
// fused N-value block reductions: one barrier pair for N sums/maxes
// (summation tree per value identical to block_sum256 -> bit-identical results)
template<int N>
__device__ __forceinline__ void block_sumN(float (&v)[N], float* scr){
  #pragma unroll
  for (int i=0;i<N;i++) v[i] = wave_sum64(v[i]);
  __syncthreads();
  if ((threadIdx.x & 63) == 0){
    int w = threadIdx.x >> 6;
    #pragma unroll
    for (int i=0;i<N;i++) scr[w*N + i] = v[i];
  }
  __syncthreads();
  #pragma unroll
  for (int i=0;i<N;i++) v[i] = scr[0*N+i] + scr[1*N+i] + scr[2*N+i] + scr[3*N+i];
}
template<int N>
__device__ __forceinline__ void block_maxN(float (&v)[N], float* scr){
  #pragma unroll
  for (int i=0;i<N;i++) v[i] = wave_max64(v[i]);
  __syncthreads();
  if ((threadIdx.x & 63) == 0){
    int w = threadIdx.x >> 6;
    #pragma unroll
    for (int i=0;i<N;i++) scr[w*N + i] = v[i];
  }
  __syncthreads();
  #pragma unroll
  for (int i=0;i<N;i++) v[i] = fmaxf(fmaxf(scr[0*N+i],scr[1*N+i]), fmaxf(scr[2*N+i],scr[3*N+i]));
}

// write-through store to coherence point (no cache maintenance)
__device__ __forceinline__ void cstore(float* p, float v){
  __hip_atomic_store(p, v, __ATOMIC_RELAXED, __HIP_MEMORY_SCOPE_AGENT);
}

// ---- workspace layout (float offsets) ----
#define WS_MEM    0          /* 1,048,576 */
#define WS_LINK   1048576    /* 4,194,304 */
#define WS_PREC   5242880    /* 2 x 16384 */
#define WS_WR     5275648    /* 65,536 */
#define WS_WW     5341184    /* 16,384 */
#define WS_USAGE  5357568    /* 16,384 */
#define WS_BAR    5373952    /* 1024 ints */
#define WS_ZONEA  5374976    /* memset extent */
#define WS_QSUM   5374976    /* 65,536 (init not required) */
#define WS_HTS    5440512    /* 21 x 32768 h slots */
#define WS_RVS    6128640    /* 21 x 16384 rvecT slots */
#define WS_XIS    6472704    /* 21 x 30144 xi slots */
#define WS_GXP    7105728    /* 2,621,440 (q gxp; c cxp) */
#define WS_ZONEC  9727168    /* 1,152,000 gemm partials */
#define WS_IMGF   10879168
#define WS_COMB   10944704
#define WS_LASTB  11010240   /* [64][1280] */
#define WS_HID1   11092160   /* [64][3000] */
#define WS_QV     11284160   /* [1280][300] */

// ------------------------- embedding -------------------------
__global__ void embed_kernel(const int* __restrict__ qst, const float* __restrict__ emb,
                             float* __restrict__ qv){
  int idx = blockIdx.x*256 + threadIdx.x;
  if (idx >= 1280*300) return;
  int m = idx / 300;
  int e = idx - m*300;
  int t = m >> 6, b = m & 63;
  int tok = qst[b*20 + t];
  qv[idx] = tanhf(emb[(size_t)tok*300 + e]);
}

// ------------------------- generic tiled f32 GEMM (float4 loads) ------------------
__global__ __launch_bounds__(256) void gemm64(
    int M, int N, int Ktot, int KS,
    const float* __restrict__ A, int lda,
    const float* __restrict__ B,
    const float* __restrict__ bias,
    float* __restrict__ out, float* __restrict__ part, int mode)
{
  __shared__ float As[32*68];
  __shared__ float Bs[32*68];
  int tid = threadIdx.x;
  int nb = blockIdx.x*64, ks = blockIdx.y, mb = blockIdx.z*64;
  int Kc = (((Ktot + KS - 1)/KS) + 3) & ~3;
  int kbeg = ks*Kc, kend = min(Ktot, kbeg + Kc);
  int tm = tid >> 4, tn = tid & 15;
  float acc[4][4];
  #pragma unroll
  for (int i=0;i<4;i++){ acc[i][0]=0.f; acc[i][1]=0.f; acc[i][2]=0.f; acc[i][3]=0.f; }

  for (int k0 = kbeg; k0 < kend; k0 += 32){
    int klim = kend - k0; if (klim > 32) klim = 32;
    #pragma unroll
    for (int i=0;i<2;i++){
      int idx = tid + i*256;
      int m = idx >> 3, kq = (idx & 7) << 2;
      if (kq < klim){
        const float* ap = A + (size_t)(mb+m)*lda + k0 + kq;
        float4 v;
        if (kq + 3 < klim) v = *(const float4*)ap;
        else { v.x=ap[0]; v.y=(kq+1<klim)?ap[1]:0.f; v.z=(kq+2<klim)?ap[2]:0.f; v.w=0.f; }
        float* as = As + m;
        as[(kq+0)*68]=v.x; as[(kq+1)*68]=v.y; as[(kq+2)*68]=v.z; as[(kq+3)*68]=v.w;
      }
    }
    #pragma unroll
    for (int i=0;i<2;i++){
      int idx = tid + i*256;
      int kk = idx >> 4, nq = (idx & 15) << 2;
      int n = nb + nq;
      float4 v = {0.f,0.f,0.f,0.f};
      if (kk < klim && n < N){
        const float* bp = B + (size_t)(k0+kk)*N + n;
        if (n + 3 < N) v = *(const float4*)bp;
        else { v.x=bp[0]; v.y=(n+1<N)?bp[1]:0.f; v.z=(n+2<N)?bp[2]:0.f; }
      }
      *(float4*)(Bs + kk*68 + nq) = v;
    }
    __syncthreads();
    for (int kk = 0; kk < klim; kk++){
      float4 a = *(const float4*)(As + kk*68 + tm*4);
      float4 bv = *(const float4*)(Bs + kk*68 + tn*4);
      acc[0][0]+=a.x*bv.x; acc[0][1]+=a.x*bv.y; acc[0][2]+=a.x*bv.z; acc[0][3]+=a.x*bv.w;
      acc[1][0]+=a.y*bv.x; acc[1][1]+=a.y*bv.y; acc[1][2]+=a.y*bv.z; acc[1][3]+=a.y*bv.w;
      acc[2][0]+=a.z*bv.x; acc[2][1]+=a.z*bv.y; acc[2][2]+=a.z*bv.z; acc[2][3]+=a.z*bv.w;
      acc[3][0]+=a.w*bv.x; acc[3][1]+=a.w*bv.y; acc[3][2]+=a.w*bv.z; acc[3][3]+=a.w*bv.w;
    }
    __syncthreads();
  }

  #pragma unroll
  for (int i=0;i<4;i++){
    int m = tm*4 + i;
    #pragma unroll
    for (int j=0;j<4;j++){
      int n = nb + tn*4 + j;
      if (n < N){
        if (mode == 0){
          part[((size_t)(ks*64 + m))*N + n] = acc[i][j];
        } else {
          float v = acc[i][j] + (bias ? bias[n] : 0.f);
          if (mode == 2) v = tanhf(v);
          out[(size_t)(mb+m)*N + n] = v;
        }
      }
    }
  }
}

__global__ void reduce64(const float* __restrict__ part, int KS, int MN4, int N,
                         const float* __restrict__ bias, float* __restrict__ out, int mode){
  int idx = blockIdx.x*256 + threadIdx.x;
  if (idx >= MN4) return;
  int base = idx*4;
  int n = base % N;
  float4 s = {0.f,0.f,0.f,0.f};
  size_t stride = (size_t)MN4*4;
  for (int p=0;p<KS;p++){
    float4 t = *(const float4*)(part + (size_t)p*stride + base);
    s.x+=t.x; s.y+=t.y; s.z+=t.z; s.w+=t.w;
  }
  if (bias){
    float4 bb = *(const float4*)(bias + n);
    s.x+=bb.x; s.y+=bb.y; s.z+=bb.z; s.w+=bb.w;
  }
  if (mode == 1){ s.x=tanhf(s.x); s.y=tanhf(s.y); s.z=tanhf(s.z); s.w=tanhf(s.w); }
  *(float4*)(out + base) = s;
}

__global__ __launch_bounds__(256) void comb_kernel(const float* __restrict__ imgf,
                                                   const float* __restrict__ qsum,
                                                   float* __restrict__ comb){
  __shared__ float s_red[4];
  int b = blockIdx.x, tid = threadIdx.x;
  float ss = 0.f;
  for (int j = tid; j < 1024; j += 256){ float v = imgf[b*1024+j]; ss += v*v; }
  ss = wave_sum64(ss);
  if ((tid & 63) == 0) s_red[tid>>6] = ss;
  __syncthreads();
  float inv = 1.0f / sqrtf(s_red[0]+s_red[1]+s_red[2]+s_red[3]);
  for (int j = tid; j < 1024; j += 256)
    comb[b*1024+j] = tanhf(imgf[b*1024+j]*inv * qsum[b*1024+j]*0.05f);
}

__global__ void tanhrvec_kernel(const float* __restrict__ rvecT, float* __restrict__ lastB){
  int idx = blockIdx.x*256 + threadIdx.x;
  if (idx >= 16384) return;
  int b = idx & 63, i = idx >> 6;
  lastB[(size_t)b*1280 + 1024 + i] = tanhf(rvecT[i*64 + b]);
}

// ===================== persistent DNC recurrence kernel ===========================
// Phase I relocated to blocks [I_LO, 256) so D blocks (0..63) skip xi compute.
#define I_LO 138

struct SD_t {
  float s_wr[1024];
  float s_Cp[4096];   // stage-8b col-sum partials [ioff][r*256+j]
  float s_Dp[4096];
  float s_rk[256];
  float s_wwnew[256], s_usage[256], s_prec[256], s_scan[256], s_sim[256];
  float s_wkey[64], s_erase[64], s_wvec[64];
  float s_red[44], s_PQ[8];   // s_red[0..3] legacy; [4..39] fused-reduction scratch
  float s_rstr[4], s_free[4], s_modes[12], s_scal[3], s_pad0[1];
};
struct SGLO_t { float red[4*768]; float g2[768]; };
struct Shm {
  float Wg[768*8];   // 24 KB: [k][8] gate weights (4 gates x 2 cols), persistent
  float Wo[768*4];   // 12 KB: [k][4] out-weight cols, persistent
  float Wi[512*4];   //  8 KB: [k][4] interface-weight cols, persistent
  union { SGLO_t glo; SD_t d; } u;
};

// O-projection for one block's 4 output cols: accO over c=0..11 (same order as
// the original fused GLO loop -> bit-identical). Returns combined value for
// this thread's (b_, col=bid*4+q_); caller applies clip.
__device__ __forceinline__ float glo_opart(const float* __restrict__ rvP,
                                           const float* __restrict__ hP,
                                           const float* __restrict__ WoL,
                                           float* __restrict__ red,
                                           float bo, int lane, int wid, int b_, int q_){
  float accO[4] = {0.f,0.f,0.f,0.f};
  for (int c = 0; c < 12; c++){
    int k0 = c*64 + wid*16;
    bool isH = (k0 >= 256);
    const float* src = isH ? (hP + (size_t)(k0-256)*64) : (rvP + (size_t)k0*64);
    float a[16];
    #pragma unroll
    for (int u=0; u<16; u++) a[u] = src[u*64 + lane];
    #pragma unroll
    for (int u=0; u<16; u++){
      int k = k0 + u;
      int orow = isH ? (k - 256) : (512 + k);
      float4 wo = *(const float4*)(WoL + (size_t)orow*4);
      float av = isH ? clipf_(a[u]) : a[u];
      accO[0] += av*wo.x; accO[1] += av*wo.y; accO[2] += av*wo.z; accO[3] += av*wo.w;
    }
  }
  #pragma unroll
  for (int j=0;j<4;j++) red[wid*256 + j*64 + lane] = accO[j];
  __syncthreads();
  float v = bo;
  #pragma unroll
  for (int w=0;w<4;w++) v += red[w*256 + q_*64 + b_];
  __syncthreads();   // red may be aliased (SD_t) right after
  return v;
}

// barmem layout (1024 ints):
//   subs  [0,256)    stride 16 : gbar group-arrival counters
//   root  @256                 : gbar root counter
//   ggen  [288,544)  stride 16 : gbar per-group release lines (16 spinners each)
//   xict  @576                 : xi completion counter (118 producers, 64 spinners)
//   subsH [608,864)  stride 16 : h completion group-arrival counters
//   rootH @896                 : h completion root (I-block spinners)

__device__ __forceinline__ void gbar(int* subs, int* root, int* ggen, int epoch){
  __syncthreads();   // compiler emits s_waitcnt vmcnt(0) before s_barrier -> all waves drained
  if (threadIdx.x == 0){
    asm volatile("s_waitcnt vmcnt(0)" ::: "memory");
    int g = blockIdx.x & 15;
    int old = __hip_atomic_fetch_add(&subs[g*16], 1, __ATOMIC_RELAXED, __HIP_MEMORY_SCOPE_AGENT);
    if (old == 16*epoch - 1){
      int r = __hip_atomic_fetch_add(root, 1, __ATOMIC_RELAXED, __HIP_MEMORY_SCOPE_AGENT);
      if (r == 16*epoch - 1){
        #pragma unroll
        for (int gg = 0; gg < 16; gg++)
          __hip_atomic_store(&ggen[gg*16], epoch, __ATOMIC_RELAXED, __HIP_MEMORY_SCOPE_AGENT);
      }
    }
    while (__hip_atomic_load(&ggen[g*16], __ATOMIC_RELAXED, __HIP_MEMORY_SCOPE_AGENT) < epoch)
      __builtin_amdgcn_s_sleep(2);
    asm volatile("" ::: "memory");
  }
  __syncthreads();
}

__global__ __launch_bounds__(256) void dnc_recur(
    int T, int outmode, int slot0,
    const float* __restrict__ xpart, const float* __restrict__ Wih_r,
    const float* __restrict__ Whh, const float* __restrict__ gb,
    const float* __restrict__ Wif, const float* __restrict__ bif,
    const float* __restrict__ Wout, const float* __restrict__ bout,
    float* __restrict__ ws, float* __restrict__ outbuf, int* __restrict__ barmem)
{
  __shared__ Shm sh;

  float* memS  = ws + WS_MEM;
  float* linkS = ws + WS_LINK;
  float* precB = ws + WS_PREC;
  float* wrS   = ws + WS_WR;
  float* wwS   = ws + WS_WW;
  float* usgS  = ws + WS_USAGE;
  float* htS   = ws + WS_HTS;
  float* rvS   = ws + WS_RVS;
  float* xiSl  = ws + WS_XIS;
  int* subs  = barmem;
  int* root  = barmem + 256;
  int* ggen  = barmem + 288;
  int* xict  = barmem + 576;
  int* subsH = barmem + 608;
  int* rootH = barmem + 896;

  int tid = threadIdx.x, bid = blockIdx.x;
  int lane = tid & 63, wid = tid >> 6;
  int b_ = tid & 63, q_ = tid >> 6;
  bool isI = (bid >= I_LO);      // xi-producer blocks (118 of them)

  // ---- load persistent weight slices into LDS (once) ----
  {
    int c2 = bid*2;
    float2* Wg2w = (float2*)sh.Wg;
    for (int e2 = tid; e2 < 3072; e2 += 256){
      int k = e2 >> 2, g = e2 & 3;
      const float* src = (k < 256) ? (Wih_r + (size_t)k*2048 + g*512 + c2)
                                   : (Whh + (size_t)(k-256)*2048 + g*512 + c2);
      Wg2w[e2] = *(const float2*)src;
    }
    int c4o = bid*4;
    float4* Wo4 = (float4*)sh.Wo;
    for (int k = tid; k < 768; k += 256)
      Wo4[k] = *(const float4*)(Wout + (size_t)k*1024 + c4o);
    if (isI){
      int c4i = (bid - I_LO)*4;
      for (int e = tid; e < 2048; e += 256){
        int k = e >> 2, c = e & 3;
        int col = c4i + c;
        sh.Wi[e] = (col < 471) ? Wif[(size_t)k*471 + col] : 0.f;
      }
    }
  }
  float bo = bout[bid*4 + q_];
  float bifv = 0.f;
  if (isI && (bid - I_LO)*4 + q_ < 471) bifv = bif[(bid - I_LO)*4 + q_];
  __syncthreads();

  float c_reg = 0.f;   // LSTM cell state (b_, col=bid*2+q_) for tid<128
  float qacc = 0.f;

  for (int t = 0; t < T; t++){
    int pp = t & 1, wp = (t + 1) & 1;
    const float* rvP1 = rvS + (size_t)(slot0+t-1)*16384;   // valid when t>0
    const float* hP1  = htS + (size_t)(slot0+t-1)*32768;

    // ======== phase GLO-gates: gates(t) + LSTM(t) — k-split over 4 waves ========
    {
      if (t > 0){
        float accG[8] = {0.f,0.f,0.f,0.f,0.f,0.f,0.f,0.f};
        for (int c = 0; c < 12; c++){
          int k0 = c*64 + wid*16;                 // wave-owned 16-k slice
          bool isH = (k0 >= 256);
          const float* src = isH ? (hP1 + (size_t)(k0-256)*64) : (rvP1 + (size_t)k0*64);
          float a[16];
          #pragma unroll
          for (int u=0; u<16; u++) a[u] = src[u*64 + lane];   // coalesced L2 reads
          #pragma unroll
          for (int u=0; u<16; u++){
            int k = k0 + u;
            float4 w0 = *(const float4*)(sh.Wg + (size_t)k*8);       // broadcast
            float4 w1 = *(const float4*)(sh.Wg + (size_t)k*8 + 4);   // broadcast
            float av = a[u];
            accG[0] += av*w0.x; accG[1] += av*w0.y; accG[2] += av*w0.z; accG[3] += av*w0.w;
            accG[4] += av*w1.x; accG[5] += av*w1.y; accG[6] += av*w1.z; accG[7] += av*w1.w;
          }
        }
        #pragma unroll
        for (int j=0;j<8;j++) sh.u.glo.red[wid*768 + j*64 + lane] = accG[j];
      }
      __syncthreads();
      // combine: thread (b_,q_) handles j = q_, q_+4
      #pragma unroll
      for (int v=0; v<2; v++){
        int j = q_ + v*4;
        int col = (j>>1)*512 + bid*2 + (j&1);
        float s = gb[col] + xpart[((size_t)(t*64 + b_))*2048 + col];
        if (t > 0){
          s += sh.u.glo.red[0*768 + j*64 + b_];
          s += sh.u.glo.red[1*768 + j*64 + b_];
          s += sh.u.glo.red[2*768 + j*64 + b_];
          s += sh.u.glo.red[3*768 + j*64 + b_];
        }
        sh.u.glo.g2[j*64 + b_] = s;
      }
      __syncthreads();
      if (tid < 128){
        int jj = q_;
        float gi = sh.u.glo.g2[(0+jj)*64 + b_];
        float gf = sh.u.glo.g2[(2+jj)*64 + b_];
        float gg = sh.u.glo.g2[(4+jj)*64 + b_];
        float go = sh.u.glo.g2[(6+jj)*64 + b_];
        float cn = sigmoidf_(gf)*c_reg + sigmoidf_(gi)*tanhf(gg);
        float hn = sigmoidf_(go)*tanhf(cn);
        c_reg = cn;
        int col = bid*2 + jj;
        cstore(&htS[(size_t)(slot0+t)*32768 + col*64 + b_], hn);
      }
    }

    // -- signal h(t) complete: hierarchical arrival, no release broadcast --
    __syncthreads();   // drains all waves' h cstores (vmcnt(0) before s_barrier)
    if (tid == 0){
      asm volatile("s_waitcnt vmcnt(0)" ::: "memory");
      int g = bid & 15;
      int old = __hip_atomic_fetch_add(&subsH[g*16], 1, __ATOMIC_RELAXED, __HIP_MEMORY_SCOPE_AGENT);
      if (old == 16*(t+1) - 1)
        __hip_atomic_fetch_add(rootH, 1, __ATOMIC_RELAXED, __HIP_MEMORY_SCOPE_AGENT);
    }

    // ======== O(t-1) for D + middle blocks (overlaps phase I on I-blocks) ========
    if (!isI && t > 0){
      float v = glo_opart(rvP1, hP1, sh.Wo, sh.u.glo.red, bo, lane, wid, b_, q_);
      qacc += clipf_(v);
    }

    // ======== phase I (blocks I_LO..255): wait h(t), xi = clip(h) @ Wif + bif ========
    if (isI){
      if (tid == 0){
        while (__hip_atomic_load(rootH, __ATOMIC_RELAXED, __HIP_MEMORY_SCOPE_AGENT) < 16*(t+1))
          __builtin_amdgcn_s_sleep(1);
        asm volatile("" ::: "memory");
      }
      __syncthreads();
      float acc[4] = {0.f,0.f,0.f,0.f};
      const float* hP = htS + (size_t)(slot0+t)*32768;
      for (int c = 0; c < 8; c++){
        int k0 = c*64 + wid*16;
        float a[16];
        #pragma unroll
        for (int u=0; u<16; u++) a[u] = hP[(size_t)(k0+u)*64 + lane];
        #pragma unroll
        for (int u=0; u<16; u++){
          float4 wv = *(const float4*)(sh.Wi + (size_t)(k0+u)*4);   // broadcast
          float ac = clipf_(a[u]);
          acc[0] += ac*wv.x; acc[1] += ac*wv.y; acc[2] += ac*wv.z; acc[3] += ac*wv.w;
        }
      }
      #pragma unroll
      for (int j=0;j<4;j++) sh.u.glo.red[wid*256 + j*64 + lane] = acc[j];
      __syncthreads();
      {
        float s = bifv;
        #pragma unroll
        for (int w=0;w<4;w++) s += sh.u.glo.red[w*256 + q_*64 + b_];
        int col = (bid - I_LO)*4 + q_;
        if (col < 471) cstore(&xiSl[(size_t)(slot0+t)*30144 + b_*471 + col], s);
      }
      // signal xi complete (stores drained by the barrier below)
      __syncthreads();
      if (tid == 0)
        __hip_atomic_fetch_add(xict, 1, __ATOMIC_RELAXED, __HIP_MEMORY_SCOPE_AGENT);
      // deferred O(t-1) — fills idle window while phase D runs
      if (t > 0){
        float v = glo_opart(rvP1, hP1, sh.Wo, sh.u.glo.red, bo, lane, wid, b_, q_);
        qacc += clipf_(v);
      }
    }

    // ======== phase D: DNC memory step (blocks 0..63) ========
    if (bid < 64){
      SD_t& sd = sh.u.d;
      int b = bid;
      const float* prec_in  = precB + pp*16384;
      float*       prec_out = precB + wp*16384;

      // ---- Stage 1a: preload private state (independent of xi) ----
      for (int e = tid; e < 1024; e += 256)
        sd.s_wr[e] = wrS[(size_t)b*1024 + e];
      float wwold = wwS[(size_t)b*256 + tid];
      sd.s_usage[tid] = usgS[(size_t)b*256 + tid];
      sd.s_prec[tid]  = prec_in[(size_t)b*256 + tid];

      // ---- wait for xi(t) (overlapped with preloads above) ----
      if (tid == 0){
        while (__hip_atomic_load(xict, __ATOMIC_RELAXED, __HIP_MEMORY_SCOPE_AGENT) < 118*(t+1))
          __builtin_amdgcn_s_sleep(1);
        asm volatile("" ::: "memory");
      }
      __syncthreads();

      // ---- Stage 1b: parse interface vector ----
      const float* xrow = xiSl + (size_t)(slot0+t)*30144 + (size_t)b*471;
      for (int idx = tid; idx < 471; idx += 256){
        float v = xrow[idx];
        if (idx < 256)       sd.s_rk[idx] = tanhf(v);
        else if (idx < 260)  sd.s_rstr[idx-256] = softplusf_(v);
        else if (idx < 324)  sd.s_wkey[idx-260] = v;
        else if (idx == 324) sd.s_scal[0] = softplusf_(v);
        else if (idx < 389)  sd.s_erase[idx-325] = sigmoidf_(v);
        else if (idx < 453)  sd.s_wvec[idx-389] = tanhf(v);
        else if (idx < 457)  sd.s_free[idx-453] = sigmoidf_(v);
        else if (idx == 457) sd.s_scal[1] = sigmoidf_(v);
        else if (idx == 458) sd.s_scal[2] = sigmoidf_(v);
        else                 sd.s_modes[idx-459] = v;
      }
      __syncthreads();

      if (tid < 4){
        float m0 = sd.s_modes[tid*3], m1 = sd.s_modes[tid*3+1], m2 = sd.s_modes[tid*3+2];
        float mx = fmaxf(m0, fmaxf(m1,m2));
        float e0 = expf(m0-mx), e1 = expf(m1-mx), e2 = expf(m2-mx);
        float s = e0+e1+e2;
        sd.s_modes[tid*3] = e0/s; sd.s_modes[tid*3+1] = e1/s; sd.s_modes[tid*3+2] = e2/s;
      }
      {
        float k = sd.s_rk[wid*64 + lane];
        float ss = wave_sum64(k*k);
        sd.s_rk[wid*64 + lane] = k / (sqrtf(ss) + EPSV);
      }
      if (wid == 0){
        float k = sd.s_wkey[lane];
        float ss = wave_sum64(k*k);
        sd.s_wkey[lane] = k / (sqrtf(ss) + EPSV);
      }

      // ---- Stage 2: usage update ----
      {
        float psi = 1.f;
        #pragma unroll
        for (int r=0;r<4;r++) psi *= (1.f - sd.s_free[r]*sd.s_wr[r*256+tid]);
        float u = (sd.s_usage[tid] + wwold - sd.s_usage[tid]*wwold) * psi;
        sd.s_usage[tid] = u;
        usgS[(size_t)b*256 + tid] = u;
      }
      __syncthreads();

      // ---- Stage 3: stable ascending rank (float4 reads) ----
      int rank_r;
      {
        float u = sd.s_usage[tid];
        int rank = 0;
        #pragma unroll 4
        for (int j4=0;j4<256;j4+=4){
          float4 uv = *(const float4*)(sd.s_usage + j4);
          rank += (uv.x < u) || (uv.x == u && (j4+0) < tid);
          rank += (uv.y < u) || (uv.y == u && (j4+1) < tid);
          rank += (uv.z < u) || (uv.z == u && (j4+2) < tid);
          rank += (uv.w < u) || (uv.w == u && (j4+3) < tid);
        }
        rank_r = rank;
        sd.s_scan[rank] = u;
      }
      __syncthreads();

      // ---- Stage 4: inclusive product scan — wave shfl scan + wave-prefix ----
      {
        float v = sd.s_scan[tid];
        #pragma unroll
        for (int off=1; off<64; off<<=1){
          float u2 = __shfl_up(v, off, 64);
          if (lane >= off) v *= u2;
        }
        if (lane == 63) sd.s_red[wid] = v;     // wave total
        __syncthreads();
        float pre = 1.f;
        if (wid > 0) pre *= sd.s_red[0];
        if (wid > 1) pre *= sd.s_red[1];
        if (wid > 2) pre *= sd.s_red[2];
        v *= pre;
        sd.s_scan[tid] = v;
        __syncthreads();
      }
      float alloc_r;
      {
        float u = sd.s_usage[tid];
        float cpe = (rank_r > 0) ? sd.s_scan[rank_r-1] : 1.f;
        alloc_r = (1.f - u) * cpe;
      }

      // ---- Stage 5: write-key cosine (row-per-thread, float4 LDS) ----
      {
        const float4* Mrow = (const float4*)(memS + (size_t)b*16384 + (size_t)tid*64);
        float nrm2 = 0.f, dt = 0.f;
        #pragma unroll
        for (int c4 = 0; c4 < 16; c4++){
          float4 mv = Mrow[c4];
          float4 wk = *(const float4*)(sd.s_wkey + c4*4);
          nrm2 += mv.x*mv.x + mv.y*mv.y + mv.z*mv.z + mv.w*mv.w;
          dt += mv.x*wk.x + mv.y*wk.y + mv.z*wk.z + mv.w*wk.w;
        }
        sd.s_sim[tid] = dt / (sqrtf(nrm2)+EPSV) * sd.s_scal[0];
      }
      __syncthreads();

      // ---- Stage 6: write softmax, ww, prec, P, Q (fused 9-sum, results -> LDS) ----
      {
        float v = sd.s_sim[tid];
        float mx = block_max256(v, sd.s_red);
        float e = expf(v - mx);
        float sm = block_sum256(e, sd.s_red);
        float cw = e / sm;
        float wwn = sd.s_scal[2] * (sd.s_scal[1]*alloc_r + (1.f - sd.s_scal[1])*cw);
        sd.s_wwnew[tid] = wwn;
        wwS[(size_t)b*256 + tid] = wwn;
        float r9[9];
        r9[0] = wwn;
        #pragma unroll
        for (int r=0;r<4;r++) r9[1+r] = sd.s_prec[tid]*sd.s_wr[r*256+tid];
        #pragma unroll
        for (int r=0;r<4;r++) r9[5+r] = wwn*sd.s_wr[r*256+tid];
        block_sumN<9>(r9, sd.s_red + 4);
        prec_out[(size_t)b*256 + tid] = (1.f - r9[0])*sd.s_prec[tid] + wwn;
        if (tid == 0){
          #pragma unroll
          for (int r=0;r<4;r++){ sd.s_PQ[r] = r9[1+r]; sd.s_PQ[4+r] = r9[5+r]; }
        }
      }
      __syncthreads();

      // ---- Stage 8a: A,B row-sums vs OLD link (float4 LDS, unroll 4) ----
      float aA[4] = {0,0,0,0}, aB[4] = {0,0,0,0};
      {
        const float4* Lrow = (const float4*)(linkS + (size_t)b*65536 + (size_t)tid*256);
        #pragma unroll 4
        for (int c4 = 0; c4 < 64; c4++){
          float4 lv = Lrow[c4];
          int j = c4*4;
          float4 wn4 = *(const float4*)(sd.s_wwnew + j);
          #pragma unroll
          for (int r=0;r<4;r++){
            float4 wr4 = *(const float4*)(sd.s_wr + r*256 + j);
            aA[r] += lv.x*wr4.x + lv.y*wr4.y + lv.z*wr4.z + lv.w*wr4.w;
            aB[r] += lv.x*(wn4.x*wr4.x) + lv.y*(wn4.y*wr4.y) + lv.z*(wn4.z*wr4.z) + lv.w*(wn4.w*wr4.w);
          }
        }
      }
      __syncthreads();

      // ---- Stage 8b: link update + C,D col-sum partials (1 barrier) ----
      {
        int cg = tid & 63, ioff = tid >> 6;
        int j0 = cg*4;
        float4 wwj4 = *(const float4*)(sd.s_wwnew + j0);
        float4 pj4  = *(const float4*)(sd.s_prec + j0);
        float cC[4][4] = {{0}}, cD[4][4] = {{0}};
        float4* Lb = (float4*)(linkS + (size_t)b*65536);
        #pragma unroll 2
        for (int it = 0; it < 64; it++){
          int i = it*4 + ioff;
          float4 lv = Lb[(size_t)i*64 + cg];
          float wwi = sd.s_wwnew[i];
          float4 ln;
          ln.x = (1.f - wwi - wwj4.x)*lv.x + wwi*pj4.x;
          ln.y = (1.f - wwi - wwj4.y)*lv.y + wwi*pj4.y;
          ln.z = (1.f - wwi - wwj4.z)*lv.z + wwi*pj4.z;
          ln.w = (1.f - wwi - wwj4.w)*lv.w + wwi*pj4.w;
          if (i >= j0 && i < j0+4){
            if (i == j0)        ln.x = 0.f;
            else if (i == j0+1) ln.y = 0.f;
            else if (i == j0+2) ln.z = 0.f;
            else                ln.w = 0.f;
          }
          Lb[(size_t)i*64 + cg] = ln;
          #pragma unroll
          for (int r=0;r<4;r++){
            float wri = sd.s_wr[r*256+i];
            float vbi = wwi*wri;
            cC[r][0] += lv.x*wri; cC[r][1] += lv.y*wri; cC[r][2] += lv.z*wri; cC[r][3] += lv.w*wri;
            cD[r][0] += lv.x*vbi; cD[r][1] += lv.y*vbi; cD[r][2] += lv.z*vbi; cD[r][3] += lv.w*vbi;
          }
        }
        #pragma unroll
        for (int r=0;r<4;r++){
          float4 cv; cv.x=cC[r][0]; cv.y=cC[r][1]; cv.z=cC[r][2]; cv.w=cC[r][3];
          float4 dv; dv.x=cD[r][0]; dv.y=cD[r][1]; dv.z=cD[r][2]; dv.w=cD[r][3];
          *(float4*)(sd.s_Cp + ioff*1024 + r*256 + j0) = cv;
          *(float4*)(sd.s_Dp + ioff*1024 + r*256 + j0) = dv;
        }
        __syncthreads();
      }

      // ---- Stage 7+9 merged: mem RMW + read-key dots (float4 LDS) ----
      float pr[4];
      {
        float4* Mrow = (float4*)(memS + (size_t)b*16384 + (size_t)tid*64);
        float wwn = sd.s_wwnew[tid];
        float nrm2 = 0.f, d0=0.f, d1=0.f, d2=0.f, d3=0.f;
        #pragma unroll
        for (int c4 = 0; c4 < 16; c4++){
          float4 mv = Mrow[c4];
          int w0 = c4*4;
          float4 er = *(const float4*)(sd.s_erase + w0);
          float4 wv = *(const float4*)(sd.s_wvec + w0);
          mv.x = mv.x*(1.f - wwn*er.x) + wwn*wv.x;
          mv.y = mv.y*(1.f - wwn*er.y) + wwn*wv.y;
          mv.z = mv.z*(1.f - wwn*er.z) + wwn*wv.z;
          mv.w = mv.w*(1.f - wwn*er.w) + wwn*wv.w;
          Mrow[c4] = mv;
          nrm2 += mv.x*mv.x + mv.y*mv.y + mv.z*mv.z + mv.w*mv.w;
          float4 rk0 = *(const float4*)(sd.s_rk + w0);
          float4 rk1 = *(const float4*)(sd.s_rk + 64 + w0);
          float4 rk2 = *(const float4*)(sd.s_rk + 128 + w0);
          float4 rk3 = *(const float4*)(sd.s_rk + 192 + w0);
          d0 += mv.x*rk0.x + mv.y*rk0.y + mv.z*rk0.z + mv.w*rk0.w;
          d1 += mv.x*rk1.x + mv.y*rk1.y + mv.z*rk1.z + mv.w*rk1.w;
          d2 += mv.x*rk2.x + mv.y*rk2.y + mv.z*rk2.z + mv.w*rk2.w;
          d3 += mv.x*rk3.x + mv.y*rk3.y + mv.z*rk3.z + mv.w*rk3.w;
        }
        float inv = 1.f/(sqrtf(nrm2)+EPSV);
        pr[0] = d0*inv*sd.s_rstr[0];
        pr[1] = d1*inv*sd.s_rstr[1];
        pr[2] = d2*inv*sd.s_rstr[2];
        pr[3] = d3*inv*sd.s_rstr[3];
      }
      // ---- read softmax: fused 4-max + 4-sum ----
      {
        float m4[4] = {pr[0], pr[1], pr[2], pr[3]};
        block_maxN<4>(m4, sd.s_red + 4);
        float e4[4];
        #pragma unroll
        for (int r=0;r<4;r++) e4[r] = expf(pr[r] - m4[r]);
        float s4[4] = {e4[0], e4[1], e4[2], e4[3]};
        block_sumN<4>(s4, sd.s_red + 4);
        #pragma unroll
        for (int r=0;r<4;r++) pr[r] = e4[r]/s4[r];
      }
      __syncthreads();

      // ---- Stage 10: fw/bw assembly + wr update (C/D partials combined here) ----
      {
        float wwn = sd.s_wwnew[tid], pn = sd.s_prec[tid];
        #pragma unroll
        for (int r=0;r<4;r++){
          float wro = sd.s_wr[r*256+tid];
          float ccv = ((sd.s_Cp[0*1024+r*256+tid] + sd.s_Cp[1*1024+r*256+tid])
                     + sd.s_Cp[2*1024+r*256+tid]) + sd.s_Cp[3*1024+r*256+tid];
          float ddv = ((sd.s_Dp[0*1024+r*256+tid] + sd.s_Dp[1*1024+r*256+tid])
                     + sd.s_Dp[2*1024+r*256+tid]) + sd.s_Dp[3*1024+r*256+tid];
          float fw  = (1.f-wwn)*aA[r] - aB[r] + wwn*(sd.s_PQ[r] - pn*wro);
          float bwv = (1.f-wwn)*ccv - ddv + pn*(sd.s_PQ[4+r] - wwn*wro);
          float wrn = sd.s_modes[r*3+0]*bwv + sd.s_modes[r*3+1]*pr[r] + sd.s_modes[r*3+2]*fw;
          wrS[(size_t)b*1024 + r*256 + tid] = wrn;
          sd.s_wr[r*256+tid] = wrn;
        }
      }
      __syncthreads();

      // ---- Stage 11: rvecT slot = (wr_new @ mem)^T — 8-deep load tile ----
      {
        int r = tid >> 6, w = tid & 63;
        const float* Mb = memS + (size_t)b*16384;
        float acc = 0.f;
        for (int n8 = 0; n8 < 256; n8 += 8){
          float m[8];
          #pragma unroll
          for (int u=0; u<8; u++) m[u] = Mb[(size_t)(n8+u)*64 + w];
          float4 w0 = *(const float4*)(sd.s_wr + r*256 + n8);
          float4 w1 = *(const float4*)(sd.s_wr + r*256 + n8 + 4);
          acc += w0.x*m[0]; acc += w0.y*m[1]; acc += w0.z*m[2]; acc += w0.w*m[3];
          acc += w1.x*m[4]; acc += w1.y*m[5]; acc += w1.z*m[6]; acc += w1.w*m[7];
        }
        cstore(&rvS[(size_t)(slot0+t)*16384 + (r*64 + w)*64 + b], acc);
      }
    }

    // single full barrier per step: orders rvec(t) (and transitively h(t), xi(t))
    gbar(subs, root, ggen, t+1);
  }

  // ======== final O(T-1) ========
  {
    float v = glo_opart(rvS + (size_t)(slot0+T-1)*16384,
                        htS + (size_t)(slot0+T-1)*32768,
                        sh.Wo, sh.u.glo.red, bo, lane, wid, b_, q_);
    v = clipf_(v);
    if (outmode == 0){
      qacc += v;
      outbuf[(size_t)b_*1024 + (bid*4 + q_)] = qacc;
    } else {
      outbuf[(size_t)b_*1280 + (bid*4 + q_)] = tanhf(v);
    }
  }
}

// ======================================================================================
extern "C" void kernel_launch(void* const* d_in, const int* in_sizes, int n_in,
                              void* d_out, int out_size, void* d_ws, size_t ws_size,
                              hipStream_t stream) {
  const float* img_feat = (const float*)d_in[0];
  const int*   qst      = (const int*)  d_in[1];
  const float* emb      = (const float*)d_in[2];
  const float* img_W    = (const float*)d_in[3];
  const float* img_b    = (const float*)d_in[4];
  const float* q_Wih    = (const float*)d_in[5];
  const float* q_Whh    = (const float*)d_in[6];
  const float* q_b      = (const float*)d_in[7];
  const float* q_Wif    = (const float*)d_in[8];
  const float* q_bif    = (const float*)d_in[9];
  const float* q_Wout   = (const float*)d_in[10];
  const float* q_bout   = (const float*)d_in[11];
  const float* c_Wih    = (const float*)d_in[12];
  const float* c_Whh    = (const float*)d_in[13];
  const float* c_b      = (const float*)d_in[14];
  const float* c_Wif    = (const float*)d_in[15];
  const float* c_bif    = (const float*)d_in[16];
  const float* c_Wout   = (const float*)d_in[17];
  const float* c_bout   = (const float*)d_in[18];
  const float* fc1_W    = (const float*)d_in[19];
  const float* fc1_b    = (const float*)d_in[20];
  const float* fc2_W    = (const float*)d_in[21];
  const float* fc2_b    = (const float*)d_in[22];

  float* ws = (float*)d_ws;
  float* qv    = ws + WS_QV;
  float* gxp   = ws + WS_GXP;
  float* zoneC = ws + WS_ZONEC;
  float* imgf  = ws + WS_IMGF;
  float* combB = ws + WS_COMB;
  float* lastB = ws + WS_LASTB;
  float* hid1  = ws + WS_HID1;
  float* qsum  = ws + WS_QSUM;
  int*   bar   = (int*)(ws + WS_BAR);

  // zero state zone (mem/link/prec/wr/ww/usage/bar)
  hipMemsetAsync(ws, 0, (size_t)WS_ZONEA*4, stream);

  // qv[(t*64+b)][300] = tanh(emb[qst])
  embed_kernel<<<1500, 256, 0, stream>>>(qst, emb, qv);

  // image fc: imgf = img_feat @ img_W + img_b  (split-K 16)
  gemm64<<<dim3(16,16,1), 256, 0, stream>>>(64, 1024, 4096, 16,
      img_feat, 4096, img_W, nullptr, nullptr, zoneC, 0);
  reduce64<<<64, 256, 0, stream>>>(zoneC, 16, 16384, 1024, img_b, imgf, 0);

  // gxp = qv @ q_Wih[0:300]
  gemm64<<<dim3(32,1,20), 256, 0, stream>>>(1280, 2048, 300, 1,
      qv, 300, q_Wih, nullptr, gxp, nullptr, 1);

  // question DNC, 20 steps (persistent), slots 0..19
  dnc_recur<<<256, 256, 0, stream>>>(20, 0, 0,
      gxp, q_Wih + (size_t)300*2048, q_Whh, q_b,
      q_Wif, q_bif, q_Wout, q_bout, ws, qsum, bar);

  // comb = tanh(l2norm(imgf) * qsum/20)
  comb_kernel<<<64, 256, 0, stream>>>(imgf, qsum, combB);

  // reset state zone for controller
  hipMemsetAsync(ws, 0, (size_t)WS_ZONEA*4, stream);

  // cxp = comb @ c_Wih[0:1024]  (split-K 4)
  gemm64<<<dim3(32,4,1), 256, 0, stream>>>(64, 2048, 1024, 4,
      combB, 1024, c_Wih, nullptr, nullptr, zoneC, 0);
  reduce64<<<128, 256, 0, stream>>>(zoneC, 4, 32768, 2048, nullptr, gxp, 0);

  // controller DNC, 1 step (persistent), slot 20 -> lastB[:, :1024]
  dnc_recur<<<256, 256, 0, stream>>>(1, 1, 20,
      gxp, c_Wih + (size_t)1024*2048, c_Whh, c_b,
      c_Wif, c_bif, c_Wout, c_bout, ws, lastB, bar);

  // lastB[:, 1024:1280] = tanh(rvec_ctrl)  (rvec slot 20)
  tanhrvec_kernel<<<64, 256, 0, stream>>>(ws + WS_RVS + (size_t)20*16384, lastB);

  // fc1: hid1 = tanh(lastB @ fc1_W + fc1_b)  (split-K 5)
  gemm64<<<dim3(47,5,1), 256, 0, stream>>>(64, 3000, 1280, 5,
      lastB, 1280, fc1_W, nullptr, nullptr, zoneC, 0);
  reduce64<<<188, 256, 0, stream>>>(zoneC, 5, 48000, 3000, fc1_b, hid1, 1);

  // fc2: logits = hid1 @ fc2_W + fc2_b  (split-K 6)
  gemm64<<<dim3(47,6,1), 256, 0, stream>>>(64, 3000, 3000, 6,
      hid1, 3000, fc2_W, nullptr, nullptr, zoneC, 0);
  reduce64<<<188, 256, 0, stream>>>(zoneC, 6, 48000, 3000, fc2_b, (float*)d_out, 0);
}

// Round 9
// 2358.039 us; speedup vs baseline: 1.2806x; 1.2806x over previous
//
#include <hip/hip_runtime.h>
#include <cmath>

#define CLIPV 20.0f
#define EPSV 1e-6f

__device__ __forceinline__ float sigmoidf_(float x){ return 1.0f/(1.0f + expf(-x)); }
__device__ __forceinline__ float softplusf_(float x){ return (x > 20.0f) ? x : log1pf(expf(x)); }
__device__ __forceinline__ float clipf_(float x){ return fminf(fmaxf(x, -CLIPV), CLIPV); }

__device__ __forceinline__ float wave_sum64(float v){
  #pragma unroll
  for (int off=32; off>=1; off>>=1) v += __shfl_xor(v, off, 64);
  return v;
}
__device__ __forceinline__ float wave_max64(float v){
  #pragma unroll
  for (int off=32; off>=1; off>>=1) v = fmaxf(v, __shfl_xor(v, off, 64));
  return v;
}
// NOTE (512-thread blocks): wave leaders of waves 4..7 write slots [4..7]; the
// combine reads only [0..3] -> result identical to the 256-thread version when
// high-half inputs are zero. s_red must have >= 8 slots.
__device__ __forceinline__ float block_sum256(float v, float* s_red){
  v = wave_sum64(v);
  __syncthreads();
  if ((threadIdx.x & 63) == 0) s_red[threadIdx.x>>6] = v;
  __syncthreads();
  return s_red[0]+s_red[1]+s_red[2]+s_red[3];
}
__device__ __forceinline__ float block_max256(float v, float* s_red){
  v = wave_max64(v);
  __syncthreads();
  if ((threadIdx.x & 63) == 0) s_red[threadIdx.x>>6] = v;
  __syncthreads();
  return fmaxf(fmaxf(s_red[0],s_red[1]), fmaxf(s_red[2],s_red[3]));
}
// fused N-value block reductions: one barrier pair for N sums/maxes.
// scr must have 8*N slots (waves 4..7 write, never read).
template<int N>
__device__ __forceinline__ void block_sumN(float (&v)[N], float* scr){
  #pragma unroll
  for (int i=0;i<N;i++) v[i] = wave_sum64(v[i]);
  __syncthreads();
  if ((threadIdx.x & 63) == 0){
    int w = threadIdx.x >> 6;
    #pragma unroll
    for (int i=0;i<N;i++) scr[w*N + i] = v[i];
  }
  __syncthreads();
  #pragma unroll
  for (int i=0;i<N;i++) v[i] = scr[0*N+i] + scr[1*N+i] + scr[2*N+i] + scr[3*N+i];
}
template<int N>
__device__ __forceinline__ void block_maxN(float (&v)[N], float* scr){
  #pragma unroll
  for (int i=0;i<N;i++) v[i] = wave_max64(v[i]);
  __syncthreads();
  if ((threadIdx.x & 63) == 0){
    int w = threadIdx.x >> 6;
    #pragma unroll
    for (int i=0;i<N;i++) scr[w*N + i] = v[i];
  }
  __syncthreads();
  #pragma unroll
  for (int i=0;i<N;i++) v[i] = fmaxf(fmaxf(scr[0*N+i],scr[1*N+i]), fmaxf(scr[2*N+i],scr[3*N+i]));
}

// write-through store to coherence point (no cache maintenance)
__device__ __forceinline__ void cstore(float* p, float v){
  __hip_atomic_store(p, v, __ATOMIC_RELAXED, __HIP_MEMORY_SCOPE_AGENT);
}

// ---- workspace layout (float offsets) ----
#define WS_MEM    0          /* 1,048,576 */
#define WS_LINK   1048576    /* 4,194,304 */
#define WS_PREC   5242880    /* 2 x 16384 */
#define WS_WR     5275648    /* 65,536 */
#define WS_WW     5341184    /* 16,384 */
#define WS_USAGE  5357568    /* 16,384 */
#define WS_BAR    5373952    /* 1024 ints */
#define WS_ZONEA  5374976    /* memset extent */
#define WS_QSUM   5374976    /* 65,536 (init not required) */
#define WS_HTS    5440512    /* 21 x 32768 h slots */
#define WS_RVS    6128640    /* 21 x 16384 rvecT slots */
#define WS_XIS    6472704    /* 21 x 30144 xi slots */
#define WS_GXP    7105728    /* 2,621,440 (q gxp; c cxp) */
#define WS_ZONEC  9727168    /* 1,152,000 gemm partials */
#define WS_IMGF   10879168
#define WS_COMB   10944704
#define WS_LASTB  11010240   /* [64][1280] */
#define WS_HID1   11092160   /* [64][3000] */
#define WS_QV     11284160   /* [1280][300] */

// ------------------------- embedding -------------------------
__global__ void embed_kernel(const int* __restrict__ qst, const float* __restrict__ emb,
                             float* __restrict__ qv){
  int idx = blockIdx.x*256 + threadIdx.x;
  if (idx >= 1280*300) return;
  int m = idx / 300;
  int e = idx - m*300;
  int t = m >> 6, b = m & 63;
  int tok = qst[b*20 + t];
  qv[idx] = tanhf(emb[(size_t)tok*300 + e]);
}

// ------------------------- generic tiled f32 GEMM (float4 loads) ------------------
__global__ __launch_bounds__(256) void gemm64(
    int M, int N, int Ktot, int KS,
    const float* __restrict__ A, int lda,
    const float* __restrict__ B,
    const float* __restrict__ bias,
    float* __restrict__ out, float* __restrict__ part, int mode)
{
  __shared__ float As[32*68];
  __shared__ float Bs[32*68];
  int tid = threadIdx.x;
  int nb = blockIdx.x*64, ks = blockIdx.y, mb = blockIdx.z*64;
  int Kc = (((Ktot + KS - 1)/KS) + 3) & ~3;
  int kbeg = ks*Kc, kend = min(Ktot, kbeg + Kc);
  int tm = tid >> 4, tn = tid & 15;
  float acc[4][4];
  #pragma unroll
  for (int i=0;i<4;i++){ acc[i][0]=0.f; acc[i][1]=0.f; acc[i][2]=0.f; acc[i][3]=0.f; }

  for (int k0 = kbeg; k0 < kend; k0 += 32){
    int klim = kend - k0; if (klim > 32) klim = 32;
    #pragma unroll
    for (int i=0;i<2;i++){
      int idx = tid + i*256;
      int m = idx >> 3, kq = (idx & 7) << 2;
      if (kq < klim){
        const float* ap = A + (size_t)(mb+m)*lda + k0 + kq;
        float4 v;
        if (kq + 3 < klim) v = *(const float4*)ap;
        else { v.x=ap[0]; v.y=(kq+1<klim)?ap[1]:0.f; v.z=(kq+2<klim)?ap[2]:0.f; v.w=0.f; }
        float* as = As + m;
        as[(kq+0)*68]=v.x; as[(kq+1)*68]=v.y; as[(kq+2)*68]=v.z; as[(kq+3)*68]=v.w;
      }
    }
    #pragma unroll
    for (int i=0;i<2;i++){
      int idx = tid + i*256;
      int kk = idx >> 4, nq = (idx & 15) << 2;
      int n = nb + nq;
      float4 v = {0.f,0.f,0.f,0.f};
      if (kk < klim && n < N){
        const float* bp = B + (size_t)(k0+kk)*N + n;
        if (n + 3 < N) v = *(const float4*)bp;
        else { v.x=bp[0]; v.y=(n+1<N)?bp[1]:0.f; v.z=(n+2<N)?bp[2]:0.f; }
      }
      *(float4*)(Bs + kk*68 + nq) = v;
    }
    __syncthreads();
    for (int kk = 0; kk < klim; kk++){
      float4 a = *(const float4*)(As + kk*68 + tm*4);
      float4 bv = *(const float4*)(Bs + kk*68 + tn*4);
      acc[0][0]+=a.x*bv.x; acc[0][1]+=a.x*bv.y; acc[0][2]+=a.x*bv.z; acc[0][3]+=a.x*bv.w;
      acc[1][0]+=a.y*bv.x; acc[1][1]+=a.y*bv.y; acc[1][2]+=a.y*bv.z; acc[1][3]+=a.y*bv.w;
      acc[2][0]+=a.z*bv.x; acc[2][1]+=a.z*bv.y; acc[2][2]+=a.z*bv.z; acc[2][3]+=a.z*bv.w;
      acc[3][0]+=a.w*bv.x; acc[3][1]+=a.w*bv.y; acc[3][2]+=a.w*bv.z; acc[3][3]+=a.w*bv.w;
    }
    __syncthreads();
  }

  #pragma unroll
  for (int i=0;i<4;i++){
    int m = tm*4 + i;
    #pragma unroll
    for (int j=0;j<4;j++){
      int n = nb + tn*4 + j;
      if (n < N){
        if (mode == 0){
          part[((size_t)(ks*64 + m))*N + n] = acc[i][j];
        } else {
          float v = acc[i][j] + (bias ? bias[n] : 0.f);
          if (mode == 2) v = tanhf(v);
          out[(size_t)(mb+m)*N + n] = v;
        }
      }
    }
  }
}

__global__ void reduce64(const float* __restrict__ part, int KS, int MN4, int N,
                         const float* __restrict__ bias, float* __restrict__ out, int mode){
  int idx = blockIdx.x*256 + threadIdx.x;
  if (idx >= MN4) return;
  int base = idx*4;
  int n = base % N;
  float4 s = {0.f,0.f,0.f,0.f};
  size_t stride = (size_t)MN4*4;
  for (int p=0;p<KS;p++){
    float4 t = *(const float4*)(part + (size_t)p*stride + base);
    s.x+=t.x; s.y+=t.y; s.z+=t.z; s.w+=t.w;
  }
  if (bias){
    float4 bb = *(const float4*)(bias + n);
    s.x+=bb.x; s.y+=bb.y; s.z+=bb.z; s.w+=bb.w;
  }
  if (mode == 1){ s.x=tanhf(s.x); s.y=tanhf(s.y); s.z=tanhf(s.z); s.w=tanhf(s.w); }
  *(float4*)(out + base) = s;
}

__global__ __launch_bounds__(256) void comb_kernel(const float* __restrict__ imgf,
                                                   const float* __restrict__ qsum,
                                                   float* __restrict__ comb){
  __shared__ float s_red[4];
  int b = blockIdx.x, tid = threadIdx.x;
  float ss = 0.f;
  for (int j = tid; j < 1024; j += 256){ float v = imgf[b*1024+j]; ss += v*v; }
  ss = wave_sum64(ss);
  if ((tid & 63) == 0) s_red[tid>>6] = ss;
  __syncthreads();
  float inv = 1.0f / sqrtf(s_red[0]+s_red[1]+s_red[2]+s_red[3]);
  for (int j = tid; j < 1024; j += 256)
    comb[b*1024+j] = tanhf(imgf[b*1024+j]*inv * qsum[b*1024+j]*0.05f);
}

__global__ void tanhrvec_kernel(const float* __restrict__ rvecT, float* __restrict__ lastB){
  int idx = blockIdx.x*256 + threadIdx.x;
  if (idx >= 16384) return;
  int b = idx & 63, i = idx >> 6;
  lastB[(size_t)b*1280 + 1024 + i] = tanhf(rvecT[i*64 + b]);
}

// ===================== persistent DNC recurrence kernel ===========================
// 512 threads/block (8 waves -> 2 waves/SIMD for latency hiding).
// Phases keep 256-thread logic (guarded tid<256) except 8a/8b/11 which use all 512.
// Phase I on blocks [I_LO, 256) so D blocks (0..63) skip xi compute.
// LDS kept UNDER 128 KiB (round-7 131,264 B build failed; suspected WG-LDS limit).
#define I_LO 138

struct SD_t {
  float s_wr[1024];
  float s_Cp[4096];   // 8b col-sum partials, 4 merged slots [io 0..3][r*256+j]
  float s_Dp[4096];
  float s_aAp[1024], s_aBp[1024];  // 8a high-half partials [r*256+row]
  float s_p11[256];   // stage-11 high-half partials
  float s_rk[256];
  float s_wwnew[256], s_usage[256], s_prec[256], s_scan[256], s_sim[256];
  float s_wkey[64], s_erase[64], s_wvec[64];
  float s_red[80], s_PQ[8];   // s_red[0..7] legacy slots; [8..79] fused scratch (8*9)
  float s_rstr[4], s_free[4], s_modes[12], s_scal[3], s_pad0[1];
};
struct SGLO_t { float red[4*768]; float g2[768]; };
struct Shm {
  float Wg[768*8];   // 24 KB: [k][8] gate weights, persistent
  float Wo[768*4];   // 12 KB: [k][4] out-weight cols, persistent
  float Wi[512*4];   //  8 KB: [k][4] interface-weight cols, persistent
  union { SGLO_t glo; SD_t d; } u;
};

// O-projection (4-wave k-split; high half only joins barriers).
__device__ __forceinline__ float glo_opart(const float* __restrict__ rvP,
                                           const float* __restrict__ hP,
                                           const float* __restrict__ WoL,
                                           float* __restrict__ red,
                                           float bo, int lane, int wid, int b_, int q_){
  int tid = threadIdx.x;
  if (tid < 256){
    float accO[4] = {0.f,0.f,0.f,0.f};
    for (int c = 0; c < 12; c++){
      int k0 = c*64 + wid*16;
      bool isH = (k0 >= 256);
      const float* src = isH ? (hP + (size_t)(k0-256)*64) : (rvP + (size_t)k0*64);
      float a[16];
      #pragma unroll
      for (int u=0; u<16; u++) a[u] = src[u*64 + lane];
      #pragma unroll
      for (int u=0; u<16; u++){
        int k = k0 + u;
        int orow = isH ? (k - 256) : (512 + k);
        float4 wo = *(const float4*)(WoL + (size_t)orow*4);
        float av = isH ? clipf_(a[u]) : a[u];
        accO[0] += av*wo.x; accO[1] += av*wo.y; accO[2] += av*wo.z; accO[3] += av*wo.w;
      }
    }
    #pragma unroll
    for (int j=0;j<4;j++) red[wid*256 + j*64 + lane] = accO[j];
  }
  __syncthreads();
  float v = bo;
  if (tid < 256){
    #pragma unroll
    for (int w=0;w<4;w++) v += red[w*256 + q_*64 + b_];
  }
  __syncthreads();   // red may be aliased (SD_t) right after
  return v;
}

// barmem layout (1024 ints): subs[0,256) s16; root@256; ggen[288,544) s16;
// xict@576; subsH[608,864) s16; rootH@896

__device__ __forceinline__ void gbar(int* subs, int* root, int* ggen, int epoch){
  __syncthreads();
  if (threadIdx.x == 0){
    asm volatile("s_waitcnt vmcnt(0)" ::: "memory");
    int g = blockIdx.x & 15;
    int old = __hip_atomic_fetch_add(&subs[g*16], 1, __ATOMIC_RELAXED, __HIP_MEMORY_SCOPE_AGENT);
    if (old == 16*epoch - 1){
      int r = __hip_atomic_fetch_add(root, 1, __ATOMIC_RELAXED, __HIP_MEMORY_SCOPE_AGENT);
      if (r == 16*epoch - 1){
        #pragma unroll
        for (int gg = 0; gg < 16; gg++)
          __hip_atomic_store(&ggen[gg*16], epoch, __ATOMIC_RELAXED, __HIP_MEMORY_SCOPE_AGENT);
      }
    }
    while (__hip_atomic_load(&ggen[g*16], __ATOMIC_RELAXED, __HIP_MEMORY_SCOPE_AGENT) < epoch)
      __builtin_amdgcn_s_sleep(2);
    asm volatile("" ::: "memory");
  }
  __syncthreads();
}

__global__ __launch_bounds__(512) void dnc_recur(
    int T, int outmode, int slot0,
    const float* __restrict__ xpart, const float* __restrict__ Wih_r,
    const float* __restrict__ Whh, const float* __restrict__ gb,
    const float* __restrict__ Wif, const float* __restrict__ bif,
    const float* __restrict__ Wout, const float* __restrict__ bout,
    float* __restrict__ ws, float* __restrict__ outbuf, int* __restrict__ barmem)
{
  __shared__ Shm sh;

  float* memS  = ws + WS_MEM;
  float* linkS = ws + WS_LINK;
  float* precB = ws + WS_PREC;
  float* wrS   = ws + WS_WR;
  float* wwS   = ws + WS_WW;
  float* usgS  = ws + WS_USAGE;
  float* htS   = ws + WS_HTS;
  float* rvS   = ws + WS_RVS;
  float* xiSl  = ws + WS_XIS;
  int* subs  = barmem;
  int* root  = barmem + 256;
  int* ggen  = barmem + 288;
  int* xict  = barmem + 576;
  int* subsH = barmem + 608;
  int* rootH = barmem + 896;

  int tid = threadIdx.x, bid = blockIdx.x;
  int lane = tid & 63, wid = tid >> 6;
  int b_ = tid & 63, q_ = tid >> 6;
  bool isI = (bid >= I_LO);

  // ---- load persistent weight slices into LDS (once) ----
  {
    int c2 = bid*2;
    float2* Wg2w = (float2*)sh.Wg;
    for (int e2 = tid; e2 < 3072; e2 += 512){
      int k = e2 >> 2, g = e2 & 3;
      const float* src = (k < 256) ? (Wih_r + (size_t)k*2048 + g*512 + c2)
                                   : (Whh + (size_t)(k-256)*2048 + g*512 + c2);
      Wg2w[e2] = *(const float2*)src;
    }
    int c4o = bid*4;
    float4* Wo4 = (float4*)sh.Wo;
    for (int k = tid; k < 768; k += 512)
      Wo4[k] = *(const float4*)(Wout + (size_t)k*1024 + c4o);
    if (isI){
      int c4i = (bid - I_LO)*4;
      for (int e = tid; e < 2048; e += 512){
        int k = e >> 2, c = e & 3;
        int col = c4i + c;
        sh.Wi[e] = (col < 471) ? Wif[(size_t)k*471 + col] : 0.f;
      }
    }
  }
  float bo = (tid < 256) ? bout[bid*4 + q_] : 0.f;
  float bifv = 0.f;
  if (isI && tid < 256 && (bid - I_LO)*4 + q_ < 471) bifv = bif[(bid - I_LO)*4 + q_];
  __syncthreads();

  float c_reg = 0.f;   // LSTM cell state (b_, col=bid*2+q_) for tid<128
  float qacc = 0.f;

  for (int t = 0; t < T; t++){
    int pp = t & 1, wp = (t + 1) & 1;
    const float* rvP1 = rvS + (size_t)(slot0+t-1)*16384;   // valid when t>0
    const float* hP1  = htS + (size_t)(slot0+t-1)*32768;

    // ======== phase GLO-gates: gates(t) + LSTM(t) — 4-wave k-split ========
    {
      if (t > 0 && tid < 256){
        float accG[8] = {0.f,0.f,0.f,0.f,0.f,0.f,0.f,0.f};
        for (int c = 0; c < 12; c++){
          int k0 = c*64 + wid*16;
          bool isH = (k0 >= 256);
          const float* src = isH ? (hP1 + (size_t)(k0-256)*64) : (rvP1 + (size_t)k0*64);
          float a[16];
          #pragma unroll
          for (int u=0; u<16; u++) a[u] = src[u*64 + lane];
          #pragma unroll
          for (int u=0; u<16; u++){
            int k = k0 + u;
            float4 w0 = *(const float4*)(sh.Wg + (size_t)k*8);
            float4 w1 = *(const float4*)(sh.Wg + (size_t)k*8 + 4);
            float av = a[u];
            accG[0] += av*w0.x; accG[1] += av*w0.y; accG[2] += av*w0.z; accG[3] += av*w0.w;
            accG[4] += av*w1.x; accG[5] += av*w1.y; accG[6] += av*w1.z; accG[7] += av*w1.w;
          }
        }
        #pragma unroll
        for (int j=0;j<8;j++) sh.u.glo.red[wid*768 + j*64 + lane] = accG[j];
      }
      __syncthreads();
      if (tid < 256){
        #pragma unroll
        for (int v=0; v<2; v++){
          int j = q_ + v*4;
          int col = (j>>1)*512 + bid*2 + (j&1);
          float s = gb[col] + xpart[((size_t)(t*64 + b_))*2048 + col];
          if (t > 0){
            s += sh.u.glo.red[0*768 + j*64 + b_];
            s += sh.u.glo.red[1*768 + j*64 + b_];
            s += sh.u.glo.red[2*768 + j*64 + b_];
            s += sh.u.glo.red[3*768 + j*64 + b_];
          }
          sh.u.glo.g2[j*64 + b_] = s;
        }
      }
      __syncthreads();
      if (tid < 128){
        int jj = q_;
        float gi = sh.u.glo.g2[(0+jj)*64 + b_];
        float gf = sh.u.glo.g2[(2+jj)*64 + b_];
        float gg = sh.u.glo.g2[(4+jj)*64 + b_];
        float go = sh.u.glo.g2[(6+jj)*64 + b_];
        float cn = sigmoidf_(gf)*c_reg + sigmoidf_(gi)*tanhf(gg);
        float hn = sigmoidf_(go)*tanhf(cn);
        c_reg = cn;
        int col = bid*2 + jj;
        cstore(&htS[(size_t)(slot0+t)*32768 + col*64 + b_], hn);
      }
    }

    // -- signal h(t) complete --
    __syncthreads();
    if (tid == 0){
      asm volatile("s_waitcnt vmcnt(0)" ::: "memory");
      int g = bid & 15;
      int old = __hip_atomic_fetch_add(&subsH[g*16], 1, __ATOMIC_RELAXED, __HIP_MEMORY_SCOPE_AGENT);
      if (old == 16*(t+1) - 1)
        __hip_atomic_fetch_add(rootH, 1, __ATOMIC_RELAXED, __HIP_MEMORY_SCOPE_AGENT);
    }

    // ======== O(t-1) for D + middle blocks ========
    if (!isI && t > 0){
      float v = glo_opart(rvP1, hP1, sh.Wo, sh.u.glo.red, bo, lane, wid, b_, q_);
      if (tid < 256) qacc += clipf_(v);
    }

    // ======== phase I (blocks I_LO..255) ========
    if (isI){
      if (tid == 0){
        while (__hip_atomic_load(rootH, __ATOMIC_RELAXED, __HIP_MEMORY_SCOPE_AGENT) < 16*(t+1))
          __builtin_amdgcn_s_sleep(1);
        asm volatile("" ::: "memory");
      }
      __syncthreads();
      const float* hP = htS + (size_t)(slot0+t)*32768;
      if (tid < 256){
        float acc[4] = {0.f,0.f,0.f,0.f};
        for (int c = 0; c < 8; c++){
          int k0 = c*64 + wid*16;
          float a[16];
          #pragma unroll
          for (int u=0; u<16; u++) a[u] = hP[(size_t)(k0+u)*64 + lane];
          #pragma unroll
          for (int u=0; u<16; u++){
            float4 wv = *(const float4*)(sh.Wi + (size_t)(k0+u)*4);
            float ac = clipf_(a[u]);
            acc[0] += ac*wv.x; acc[1] += ac*wv.y; acc[2] += ac*wv.z; acc[3] += ac*wv.w;
          }
        }
        #pragma unroll
        for (int j=0;j<4;j++) sh.u.glo.red[wid*256 + j*64 + lane] = acc[j];
      }
      __syncthreads();
      if (tid < 256){
        float s = bifv;
        #pragma unroll
        for (int w=0;w<4;w++) s += sh.u.glo.red[w*256 + q_*64 + b_];
        int col = (bid - I_LO)*4 + q_;
        if (col < 471) cstore(&xiSl[(size_t)(slot0+t)*30144 + b_*471 + col], s);
      }
      __syncthreads();
      if (tid == 0)
        __hip_atomic_fetch_add(xict, 1, __ATOMIC_RELAXED, __HIP_MEMORY_SCOPE_AGENT);
      if (t > 0){
        float v = glo_opart(rvP1, hP1, sh.Wo, sh.u.glo.red, bo, lane, wid, b_, q_);
        if (tid < 256) qacc += clipf_(v);
      }
    }

    // ======== phase D: DNC memory step (blocks 0..63) ========
    if (bid < 64){
      SD_t& sd = sh.u.d;
      int b = bid;
      const float* prec_in  = precB + pp*16384;
      float*       prec_out = precB + wp*16384;

      // ---- Stage 1a: preload private state (independent of xi) ----
      for (int e = tid; e < 1024; e += 512)
        sd.s_wr[e] = wrS[(size_t)b*1024 + e];
      float wwold = 0.f;
      if (tid < 256){
        wwold = wwS[(size_t)b*256 + tid];
        sd.s_usage[tid] = usgS[(size_t)b*256 + tid];
        sd.s_prec[tid]  = prec_in[(size_t)b*256 + tid];
      }

      // ---- wait for xi(t) ----
      if (tid == 0){
        while (__hip_atomic_load(xict, __ATOMIC_RELAXED, __HIP_MEMORY_SCOPE_AGENT) < 118*(t+1))
          __builtin_amdgcn_s_sleep(1);
        asm volatile("" ::: "memory");
      }
      __syncthreads();

      // ---- Stage 1b: parse interface vector ----
      const float* xrow = xiSl + (size_t)(slot0+t)*30144 + (size_t)b*471;
      for (int idx = tid; idx < 471; idx += 512){
        float v = xrow[idx];
        if (idx < 256)       sd.s_rk[idx] = tanhf(v);
        else if (idx < 260)  sd.s_rstr[idx-256] = softplusf_(v);
        else if (idx < 324)  sd.s_wkey[idx-260] = v;
        else if (idx == 324) sd.s_scal[0] = softplusf_(v);
        else if (idx < 389)  sd.s_erase[idx-325] = sigmoidf_(v);
        else if (idx < 453)  sd.s_wvec[idx-389] = tanhf(v);
        else if (idx < 457)  sd.s_free[idx-453] = sigmoidf_(v);
        else if (idx == 457) sd.s_scal[1] = sigmoidf_(v);
        else if (idx == 458) sd.s_scal[2] = sigmoidf_(v);
        else                 sd.s_modes[idx-459] = v;
      }
      __syncthreads();

      if (tid < 4){
        float m0 = sd.s_modes[tid*3], m1 = sd.s_modes[tid*3+1], m2 = sd.s_modes[tid*3+2];
        float mx = fmaxf(m0, fmaxf(m1,m2));
        float e0 = expf(m0-mx), e1 = expf(m1-mx), e2 = expf(m2-mx);
        float s = e0+e1+e2;
        sd.s_modes[tid*3] = e0/s; sd.s_modes[tid*3+1] = e1/s; sd.s_modes[tid*3+2] = e2/s;
      }
      if (wid < 4){
        float k = sd.s_rk[wid*64 + lane];
        float ss = wave_sum64(k*k);
        sd.s_rk[wid*64 + lane] = k / (sqrtf(ss) + EPSV);
      }
      if (wid == 0){
        float k = sd.s_wkey[lane];
        float ss = wave_sum64(k*k);
        sd.s_wkey[lane] = k / (sqrtf(ss) + EPSV);
      }

      // ---- Stage 2: usage update ----
      if (tid < 256){
        float psi = 1.f;
        #pragma unroll
        for (int r=0;r<4;r++) psi *= (1.f - sd.s_free[r]*sd.s_wr[r*256+tid]);
        float u = (sd.s_usage[tid] + wwold - sd.s_usage[tid]*wwold) * psi;
        sd.s_usage[tid] = u;
        usgS[(size_t)b*256 + tid] = u;
      }
      __syncthreads();

      // ---- Stage 3: stable ascending rank ----
      int rank_r = 0;
      if (tid < 256){
        float u = sd.s_usage[tid];
        int rank = 0;
        #pragma unroll 4
        for (int j4=0;j4<256;j4+=4){
          float4 uv = *(const float4*)(sd.s_usage + j4);
          rank += (uv.x < u) || (uv.x == u && (j4+0) < tid);
          rank += (uv.y < u) || (uv.y == u && (j4+1) < tid);
          rank += (uv.z < u) || (uv.z == u && (j4+2) < tid);
          rank += (uv.w < u) || (uv.w == u && (j4+3) < tid);
        }
        rank_r = rank;
        sd.s_scan[rank] = u;
      }
      __syncthreads();

      // ---- Stage 4: inclusive product scan ----
      {
        float v = 0.f;
        if (tid < 256){
          v = sd.s_scan[tid];
          #pragma unroll
          for (int off=1; off<64; off<<=1){
            float u2 = __shfl_up(v, off, 64);
            if (lane >= off) v *= u2;
          }
          if (lane == 63) sd.s_red[wid] = v;
        }
        __syncthreads();
        if (tid < 256){
          float pre = 1.f;
          if (wid > 0) pre *= sd.s_red[0];
          if (wid > 1) pre *= sd.s_red[1];
          if (wid > 2) pre *= sd.s_red[2];
          v *= pre;
          sd.s_scan[tid] = v;
        }
        __syncthreads();
      }
      float alloc_r = 0.f;
      if (tid < 256){
        float u = sd.s_usage[tid];
        float cpe = (rank_r > 0) ? sd.s_scan[rank_r-1] : 1.f;
        alloc_r = (1.f - u) * cpe;
      }

      // ---- Stage 5: write-key cosine ----
      if (tid < 256){
        const float4* Mrow = (const float4*)(memS + (size_t)b*16384 + (size_t)tid*64);
        float nrm2 = 0.f, dt = 0.f;
        #pragma unroll
        for (int c4 = 0; c4 < 16; c4++){
          float4 mv = Mrow[c4];
          int w0 = c4*4;
          nrm2 += mv.x*mv.x + mv.y*mv.y + mv.z*mv.z + mv.w*mv.w;
          dt += mv.x*sd.s_wkey[w0] + mv.y*sd.s_wkey[w0+1] + mv.z*sd.s_wkey[w0+2] + mv.w*sd.s_wkey[w0+3];
        }
        sd.s_sim[tid] = dt / (sqrtf(nrm2)+EPSV) * sd.s_scal[0];
      }
      __syncthreads();

      // ---- Stage 6: write softmax, ww, prec, P, Q ----
      {
        float v = (tid < 256) ? sd.s_sim[tid] : 0.f;
        float mx = block_max256(v, sd.s_red);
        float e = expf(v - mx);
        float sm = block_sum256((tid < 256) ? e : 0.f, sd.s_red);
        float wwn = 0.f, prv = 0.f;
        if (tid < 256){
          float cw = e / sm;
          wwn = sd.s_scal[2] * (sd.s_scal[1]*alloc_r + (1.f - sd.s_scal[1])*cw);
          sd.s_wwnew[tid] = wwn;
          wwS[(size_t)b*256 + tid] = wwn;
          prv = sd.s_prec[tid];
        }
        float r9[9];
        r9[0] = wwn;
        #pragma unroll
        for (int r=0;r<4;r++){
          float wrv = (tid < 256) ? sd.s_wr[r*256+tid] : 0.f;
          r9[1+r] = prv*wrv;
          r9[5+r] = wwn*wrv;
        }
        block_sumN<9>(r9, sd.s_red + 8);
        if (tid < 256)
          prec_out[(size_t)b*256 + tid] = (1.f - r9[0])*prv + wwn;
        if (tid == 0){
          #pragma unroll
          for (int r=0;r<4;r++){ sd.s_PQ[r] = r9[1+r]; sd.s_PQ[4+r] = r9[5+r]; }
        }
      }
      __syncthreads();

      // ---- Stage 8a: A,B row-sums vs OLD link — 512-thread (2 threads/row) ----
      float aA[4] = {0,0,0,0}, aB[4] = {0,0,0,0};
      {
        int row = tid & 255, half = tid >> 8;
        const float4* Lrow = (const float4*)(linkS + (size_t)b*65536 + (size_t)row*256);
        int c4e = half*32 + 32;
        for (int c4 = half*32; c4 < c4e; c4++){
          float4 lv = Lrow[c4];
          int j = c4*4;
          float w0n = sd.s_wwnew[j], w1n = sd.s_wwnew[j+1], w2n = sd.s_wwnew[j+2], w3n = sd.s_wwnew[j+3];
          #pragma unroll
          for (int r=0;r<4;r++){
            float wr0 = sd.s_wr[r*256+j], wr1 = sd.s_wr[r*256+j+1];
            float wr2 = sd.s_wr[r*256+j+2], wr3 = sd.s_wr[r*256+j+3];
            aA[r] += lv.x*wr0 + lv.y*wr1 + lv.z*wr2 + lv.w*wr3;
            aB[r] += lv.x*(w0n*wr0) + lv.y*(w1n*wr1) + lv.z*(w2n*wr2) + lv.w*(w3n*wr3);
          }
        }
        if (half){
          #pragma unroll
          for (int r=0;r<4;r++){ sd.s_aAp[r*256+row] = aA[r]; sd.s_aBp[r*256+row] = aB[r]; }
        }
        __syncthreads();
        if (!half){
          #pragma unroll
          for (int r=0;r<4;r++){ aA[r] += sd.s_aAp[r*256+row]; aB[r] += sd.s_aBp[r*256+row]; }
        }
      }

      // ---- Stage 8b: link update + C,D col-sum partials — 8-way row split,
      //      merged into 4 LDS slots (ioff>=4 store; sync; ioff<4 read-add-store) ----
      {
        int cg = tid & 63, ioff = tid >> 6;   // ioff 0..7
        int j0 = cg*4;
        float wwj0 = sd.s_wwnew[j0], wwj1 = sd.s_wwnew[j0+1], wwj2 = sd.s_wwnew[j0+2], wwj3 = sd.s_wwnew[j0+3];
        float pj0 = sd.s_prec[j0], pj1 = sd.s_prec[j0+1], pj2 = sd.s_prec[j0+2], pj3 = sd.s_prec[j0+3];
        float cC[4][4] = {{0}}, cD[4][4] = {{0}};
        float4* Lb = (float4*)(linkS + (size_t)b*65536);
        for (int it = 0; it < 32; it++){
          int i = it*8 + ioff;
          float4 lv = Lb[(size_t)i*64 + cg];
          float wwi = sd.s_wwnew[i];
          float4 ln;
          ln.x = (1.f - wwi - wwj0)*lv.x + wwi*pj0;
          ln.y = (1.f - wwi - wwj1)*lv.y + wwi*pj1;
          ln.z = (1.f - wwi - wwj2)*lv.z + wwi*pj2;
          ln.w = (1.f - wwi - wwj3)*lv.w + wwi*pj3;
          if (i >= j0 && i < j0+4){
            if (i == j0)        ln.x = 0.f;
            else if (i == j0+1) ln.y = 0.f;
            else if (i == j0+2) ln.z = 0.f;
            else                ln.w = 0.f;
          }
          Lb[(size_t)i*64 + cg] = ln;
          #pragma unroll
          for (int r=0;r<4;r++){
            float wri = sd.s_wr[r*256+i];
            float vbi = wwi*wri;
            cC[r][0] += lv.x*wri; cC[r][1] += lv.y*wri; cC[r][2] += lv.z*wri; cC[r][3] += lv.w*wri;
            cD[r][0] += lv.x*vbi; cD[r][1] += lv.y*vbi; cD[r][2] += lv.z*vbi; cD[r][3] += lv.w*vbi;
          }
        }
        if (ioff >= 4){
          int io = ioff - 4;
          #pragma unroll
          for (int r=0;r<4;r++){
            float4 cv; cv.x=cC[r][0]; cv.y=cC[r][1]; cv.z=cC[r][2]; cv.w=cC[r][3];
            float4 dv; dv.x=cD[r][0]; dv.y=cD[r][1]; dv.z=cD[r][2]; dv.w=cD[r][3];
            *(float4*)(sd.s_Cp + io*1024 + r*256 + j0) = cv;
            *(float4*)(sd.s_Dp + io*1024 + r*256 + j0) = dv;
          }
        }
        __syncthreads();
        if (ioff < 4){
          #pragma unroll
          for (int r=0;r<4;r++){
            float4 cv = *(const float4*)(sd.s_Cp + ioff*1024 + r*256 + j0);
            float4 dv = *(const float4*)(sd.s_Dp + ioff*1024 + r*256 + j0);
            cv.x += cC[r][0]; cv.y += cC[r][1]; cv.z += cC[r][2]; cv.w += cC[r][3];
            dv.x += cD[r][0]; dv.y += cD[r][1]; dv.z += cD[r][2]; dv.w += cD[r][3];
            *(float4*)(sd.s_Cp + ioff*1024 + r*256 + j0) = cv;
            *(float4*)(sd.s_Dp + ioff*1024 + r*256 + j0) = dv;
          }
        }
        __syncthreads();
      }

      // ---- Stage 7+9 merged: mem RMW + read-key dots ----
      float pr[4] = {0.f,0.f,0.f,0.f};
      if (tid < 256){
        float4* Mrow = (float4*)(memS + (size_t)b*16384 + (size_t)tid*64);
        float wwn = sd.s_wwnew[tid];
        float nrm2 = 0.f, d0=0.f, d1=0.f, d2=0.f, d3=0.f;
        #pragma unroll
        for (int c4 = 0; c4 < 16; c4++){
          float4 mv = Mrow[c4];
          int w0 = c4*4;
          mv.x = mv.x*(1.f - wwn*sd.s_erase[w0+0]) + wwn*sd.s_wvec[w0+0];
          mv.y = mv.y*(1.f - wwn*sd.s_erase[w0+1]) + wwn*sd.s_wvec[w0+1];
          mv.z = mv.z*(1.f - wwn*sd.s_erase[w0+2]) + wwn*sd.s_wvec[w0+2];
          mv.w = mv.w*(1.f - wwn*sd.s_erase[w0+3]) + wwn*sd.s_wvec[w0+3];
          Mrow[c4] = mv;
          nrm2 += mv.x*mv.x + mv.y*mv.y + mv.z*mv.z + mv.w*mv.w;
          d0 += mv.x*sd.s_rk[w0] + mv.y*sd.s_rk[w0+1] + mv.z*sd.s_rk[w0+2] + mv.w*sd.s_rk[w0+3];
          d1 += mv.x*sd.s_rk[64+w0] + mv.y*sd.s_rk[64+w0+1] + mv.z*sd.s_rk[64+w0+2] + mv.w*sd.s_rk[64+w0+3];
          d2 += mv.x*sd.s_rk[128+w0] + mv.y*sd.s_rk[128+w0+1] + mv.z*sd.s_rk[128+w0+2] + mv.w*sd.s_rk[128+w0+3];
          d3 += mv.x*sd.s_rk[192+w0] + mv.y*sd.s_rk[192+w0+1] + mv.z*sd.s_rk[192+w0+2] + mv.w*sd.s_rk[192+w0+3];
        }
        float inv = 1.f/(sqrtf(nrm2)+EPSV);
        pr[0] = d0*inv*sd.s_rstr[0];
        pr[1] = d1*inv*sd.s_rstr[1];
        pr[2] = d2*inv*sd.s_rstr[2];
        pr[3] = d3*inv*sd.s_rstr[3];
      }
      // ---- read softmax: fused 4-max + 4-sum ----
      {
        float m4[4] = {pr[0], pr[1], pr[2], pr[3]};
        block_maxN<4>(m4, sd.s_red + 8);
        float e4[4];
        #pragma unroll
        for (int r=0;r<4;r++) e4[r] = expf(pr[r] - m4[r]);
        float s4[4];
        #pragma unroll
        for (int r=0;r<4;r++) s4[r] = (tid < 256) ? e4[r] : 0.f;
        block_sumN<4>(s4, sd.s_red + 8);
        if (tid < 256){
          #pragma unroll
          for (int r=0;r<4;r++) pr[r] = e4[r]/s4[r];
        }
      }
      __syncthreads();

      // ---- Stage 10: fw/bw assembly + wr update (combine 4 merged C/D slots) ----
      if (tid < 256){
        float wwn = sd.s_wwnew[tid], pn = sd.s_prec[tid];
        #pragma unroll
        for (int r=0;r<4;r++){
          float wro = sd.s_wr[r*256+tid];
          float ccv = sd.s_Cp[0*1024+r*256+tid];
          float ddv = sd.s_Dp[0*1024+r*256+tid];
          #pragma unroll
          for (int io=1; io<4; io++){
            ccv += sd.s_Cp[io*1024+r*256+tid];
            ddv += sd.s_Dp[io*1024+r*256+tid];
          }
          float fw  = (1.f-wwn)*aA[r] - aB[r] + wwn*(sd.s_PQ[r] - pn*wro);
          float bwv = (1.f-wwn)*ccv - ddv + pn*(sd.s_PQ[4+r] - wwn*wro);
          float wrn = sd.s_modes[r*3+0]*bwv + sd.s_modes[r*3+1]*pr[r] + sd.s_modes[r*3+2]*fw;
          wrS[(size_t)b*1024 + r*256 + tid] = wrn;
          sd.s_wr[r*256+tid] = wrn;
        }
      }
      __syncthreads();

      // ---- Stage 11: rvecT = (wr_new @ mem)^T — 2 threads/output ----
      {
        int r = (tid >> 6) & 3, w = tid & 63, half = tid >> 8;
        const float* Mb = memS + (size_t)b*16384;
        float acc = 0.f;
        int n0 = half*128, n1 = n0 + 128;
        for (int n = n0; n < n1; n++) acc += sd.s_wr[r*256+n]*Mb[(size_t)n*64 + w];
        if (half) sd.s_p11[r*64 + w] = acc;
        __syncthreads();
        if (!half)
          cstore(&rvS[(size_t)(slot0+t)*16384 + (r*64 + w)*64 + b], acc + sd.s_p11[r*64 + w]);
      }
    }

    // single full barrier per step
    gbar(subs, root, ggen, t+1);
  }

  // ======== final O(T-1) ========
  {
    float v = glo_opart(rvS + (size_t)(slot0+T-1)*16384,
                        htS + (size_t)(slot0+T-1)*32768,
                        sh.Wo, sh.u.glo.red, bo, lane, wid, b_, q_);
    if (tid < 256){
      v = clipf_(v);
      if (outmode == 0){
        qacc += v;
        outbuf[(size_t)b_*1024 + (bid*4 + q_)] = qacc;
      } else {
        outbuf[(size_t)b_*1280 + (bid*4 + q_)] = tanhf(v);
      }
    }
  }
}

// ======================================================================================
extern "C" void kernel_launch(void* const* d_in, const int* in_sizes, int n_in,
                              void* d_out, int out_size, void* d_ws, size_t ws_size,
                              hipStream_t stream) {
  const float* img_feat = (const float*)d_in[0];
  const int*   qst      = (const int*)  d_in[1];
  const float* emb      = (const float*)d_in[2];
  const float* img_W    = (const float*)d_in[3];
  const float* img_b    = (const float*)d_in[4];
  const float* q_Wih    = (const float*)d_in[5];
  const float* q_Whh    = (const float*)d_in[6];
  const float* q_b      = (const float*)d_in[7];
  const float* q_Wif    = (const float*)d_in[8];
  const float* q_bif    = (const float*)d_in[9];
  const float* q_Wout   = (const float*)d_in[10];
  const float* q_bout   = (const float*)d_in[11];
  const float* c_Wih    = (const float*)d_in[12];
  const float* c_Whh    = (const float*)d_in[13];
  const float* c_b      = (const float*)d_in[14];
  const float* c_Wif    = (const float*)d_in[15];
  const float* c_bif    = (const float*)d_in[16];
  const float* c_Wout   = (const float*)d_in[17];
  const float* c_bout   = (const float*)d_in[18];
  const float* fc1_W    = (const float*)d_in[19];
  const float* fc1_b    = (const float*)d_in[20];
  const float* fc2_W    = (const float*)d_in[21];
  const float* fc2_b    = (const float*)d_in[22];

  float* ws = (float*)d_ws;
  float* qv    = ws + WS_QV;
  float* gxp   = ws + WS_GXP;
  float* zoneC = ws + WS_ZONEC;
  float* imgf  = ws + WS_IMGF;
  float* combB = ws + WS_COMB;
  float* lastB = ws + WS_LASTB;
  float* hid1  = ws + WS_HID1;
  float* qsum  = ws + WS_QSUM;
  int*   bar   = (int*)(ws + WS_BAR);

  // zero state zone (mem/link/prec/wr/ww/usage/bar)
  hipMemsetAsync(ws, 0, (size_t)WS_ZONEA*4, stream);

  // qv[(t*64+b)][300] = tanh(emb[qst])
  embed_kernel<<<1500, 256, 0, stream>>>(qst, emb, qv);

  // image fc: imgf = img_feat @ img_W + img_b  (split-K 16)
  gemm64<<<dim3(16,16,1), 256, 0, stream>>>(64, 1024, 4096, 16,
      img_feat, 4096, img_W, nullptr, nullptr, zoneC, 0);
  reduce64<<<64, 256, 0, stream>>>(zoneC, 16, 16384, 1024, img_b, imgf, 0);

  // gxp = qv @ q_Wih[0:300]
  gemm64<<<dim3(32,1,20), 256, 0, stream>>>(1280, 2048, 300, 1,
      qv, 300, q_Wih, nullptr, gxp, nullptr, 1);

  // question DNC, 20 steps (persistent, 512 threads), slots 0..19
  dnc_recur<<<256, 512, 0, stream>>>(20, 0, 0,
      gxp, q_Wih + (size_t)300*2048, q_Whh, q_b,
      q_Wif, q_bif, q_Wout, q_bout, ws, qsum, bar);

  // comb = tanh(l2norm(imgf) * qsum/20)
  comb_kernel<<<64, 256, 0, stream>>>(imgf, qsum, combB);

  // reset state zone for controller
  hipMemsetAsync(ws, 0, (size_t)WS_ZONEA*4, stream);

  // cxp = comb @ c_Wih[0:1024]  (split-K 4)
  gemm64<<<dim3(32,4,1), 256, 0, stream>>>(64, 2048, 1024, 4,
      combB, 1024, c_Wih, nullptr, nullptr, zoneC, 0);
  reduce64<<<128, 256, 0, stream>>>(zoneC, 4, 32768, 2048, nullptr, gxp, 0);

  // controller DNC, 1 step (persistent, 512 threads), slot 20 -> lastB[:, :1024]
  dnc_recur<<<256, 512, 0, stream>>>(1, 1, 20,
      gxp, c_Wih + (size_t)1024*2048, c_Whh, c_b,
      c_Wif, c_bif, c_Wout, c_bout, ws, lastB, bar);

  // lastB[:, 1024:1280] = tanh(rvec_ctrl)  (rvec slot 20)
  tanhrvec_kernel<<<64, 256, 0, stream>>>(ws + WS_RVS + (size_t)20*16384, lastB);

  // fc1: hid1 = tanh(lastB @ fc1_W + fc1_b)  (split-K 5)
  gemm64<<<dim3(47,5,1), 256, 0, stream>>>(64, 3000, 1280, 5,
      lastB, 1280, fc1_W, nullptr, nullptr, zoneC, 0);
  reduce64<<<188, 256, 0, stream>>>(zoneC, 5, 48000, 3000, fc1_b, hid1, 1);

  // fc2: logits = hid1 @ fc2_W + fc2_b  (split-K 6)
  gemm64<<<dim3(47,6,1), 256, 0, stream>>>(64, 3000, 3000, 6,
      hid1, 3000, fc2_W, nullptr, nullptr, zoneC, 0);
  reduce64<<<188, 256, 0, stream>>>(zoneC, 6, 48000, 3000, fc2_b, (float*)d_out, 0);
}

// Round 10
// 2064.856 us; speedup vs baseline: 1.4624x; 1.1420x over previous
//
#include <hip/hip_runtime.h>
#include <cmath>

#define CLIPV 20.0f
#define EPSV 1e-6f

__device__ __forceinline__ float sigmoidf_(float x){ return 1.0f/(1.0f + expf(-x)); }
__device__ __forceinline__ float softplusf_(float x){ return (x > 20.0f) ? x : log1pf(expf(x)); }
__device__ __forceinline__ float clipf_(float x){ return fminf(fmaxf(x, -CLIPV), CLIPV); }

__device__ __forceinline__ float wave_sum64(float v){
  #pragma unroll
  for (int off=32; off>=1; off>>=1) v += __shfl_xor(v, off, 64);
  return v;
}
__device__ __forceinline__ float wave_max64(float v){
  #pragma unroll
  for (int off=32; off>=1; off>>=1) v = fmaxf(v, __shfl_xor(v, off, 64));
  return v;
}
__device__ __forceinline__ float block_sum256(float v, float* s_red){
  v = wave_sum64(v);
  __syncthreads();
  if ((threadIdx.x & 63) == 0) s_red[threadIdx.x>>6] = v;
  __syncthreads();
  return s_red[0]+s_red[1]+s_red[2]+s_red[3];
}
__device__ __forceinline__ float block_max256(float v, float* s_red){
  v = wave_max64(v);
  __syncthreads();
  if ((threadIdx.x & 63) == 0) s_red[threadIdx.x>>6] = v;
  __syncthreads();
  return fmaxf(fmaxf(s_red[0],s_red[1]), fmaxf(s_red[2],s_red[3]));
}
// fused N-value block reductions: one barrier pair for N sums/maxes
// (summation tree per value identical to block_sum256 -> bit-identical results)
template<int N>
__device__ __forceinline__ void block_sumN(float (&v)[N], float* scr){
  #pragma unroll
  for (int i=0;i<N;i++) v[i] = wave_sum64(v[i]);
  __syncthreads();
  if ((threadIdx.x & 63) == 0){
    int w = threadIdx.x >> 6;
    #pragma unroll
    for (int i=0;i<N;i++) scr[w*N + i] = v[i];
  }
  __syncthreads();
  #pragma unroll
  for (int i=0;i<N;i++) v[i] = scr[0*N+i] + scr[1*N+i] + scr[2*N+i] + scr[3*N+i];
}
template<int N>
__device__ __forceinline__ void block_maxN(float (&v)[N], float* scr){
  #pragma unroll
  for (int i=0;i<N;i++) v[i] = wave_max64(v[i]);
  __syncthreads();
  if ((threadIdx.x & 63) == 0){
    int w = threadIdx.x >> 6;
    #pragma unroll
    for (int i=0;i<N;i++) scr[w*N + i] = v[i];
  }
  __syncthreads();
  #pragma unroll
  for (int i=0;i<N;i++) v[i] = fmaxf(fmaxf(scr[0*N+i],scr[1*N+i]), fmaxf(scr[2*N+i],scr[3*N+i]));
}

// write-through store to coherence point (no cache maintenance)
__device__ __forceinline__ void cstore(float* p, float v){
  __hip_atomic_store(p, v, __ATOMIC_RELAXED, __HIP_MEMORY_SCOPE_AGENT);
}

// ---- workspace layout (float offsets) ----
#define WS_MEM    0          /* 1,048,576 */
#define WS_LINK   1048576    /* 4,194,304 */
#define WS_PREC   5242880    /* 2 x 16384 */
#define WS_WR     5275648    /* 65,536 */
#define WS_WW     5341184    /* 16,384 */
#define WS_USAGE  5357568    /* 16,384 */
#define WS_BAR    5373952    /* 1024 ints */
#define WS_ZONEA  5374976    /* memset extent */
#define WS_QSUM   5374976    /* 65,536 (init not required) */
#define WS_HTS    5440512    /* 21 x 32768 h slots */
#define WS_RVS    6128640    /* 21 x 16384 rvecT slots */
#define WS_XIS    6472704    /* 21 x 30144 xi slots */
#define WS_GXP    7105728    /* 2,621,440 (q gxp; c cxp) */
#define WS_ZONEC  9727168    /* 1,152,000 gemm partials */
#define WS_IMGF   10879168
#define WS_COMB   10944704
#define WS_LASTB  11010240   /* [64][1280] */
#define WS_HID1   11092160   /* [64][3000] */
#define WS_QV     11284160   /* [1280][300] */

// ------------------------- embedding -------------------------
__global__ void embed_kernel(const int* __restrict__ qst, const float* __restrict__ emb,
                             float* __restrict__ qv){
  int idx = blockIdx.x*256 + threadIdx.x;
  if (idx >= 1280*300) return;
  int m = idx / 300;
  int e = idx - m*300;
  int t = m >> 6, b = m & 63;
  int tok = qst[b*20 + t];
  qv[idx] = tanhf(emb[(size_t)tok*300 + e]);
}

// ------------------------- generic tiled f32 GEMM (float4 loads) ------------------
__global__ __launch_bounds__(256) void gemm64(
    int M, int N, int Ktot, int KS,
    const float* __restrict__ A, int lda,
    const float* __restrict__ B,
    const float* __restrict__ bias,
    float* __restrict__ out, float* __restrict__ part, int mode)
{
  __shared__ float As[32*68];
  __shared__ float Bs[32*68];
  int tid = threadIdx.x;
  int nb = blockIdx.x*64, ks = blockIdx.y, mb = blockIdx.z*64;
  int Kc = (((Ktot + KS - 1)/KS) + 3) & ~3;
  int kbeg = ks*Kc, kend = min(Ktot, kbeg + Kc);
  int tm = tid >> 4, tn = tid & 15;
  float acc[4][4];
  #pragma unroll
  for (int i=0;i<4;i++){ acc[i][0]=0.f; acc[i][1]=0.f; acc[i][2]=0.f; acc[i][3]=0.f; }

  for (int k0 = kbeg; k0 < kend; k0 += 32){
    int klim = kend - k0; if (klim > 32) klim = 32;
    #pragma unroll
    for (int i=0;i<2;i++){
      int idx = tid + i*256;
      int m = idx >> 3, kq = (idx & 7) << 2;
      if (kq < klim){
        const float* ap = A + (size_t)(mb+m)*lda + k0 + kq;
        float4 v;
        if (kq + 3 < klim) v = *(const float4*)ap;
        else { v.x=ap[0]; v.y=(kq+1<klim)?ap[1]:0.f; v.z=(kq+2<klim)?ap[2]:0.f; v.w=0.f; }
        float* as = As + m;
        as[(kq+0)*68]=v.x; as[(kq+1)*68]=v.y; as[(kq+2)*68]=v.z; as[(kq+3)*68]=v.w;
      }
    }
    #pragma unroll
    for (int i=0;i<2;i++){
      int idx = tid + i*256;
      int kk = idx >> 4, nq = (idx & 15) << 2;
      int n = nb + nq;
      float4 v = {0.f,0.f,0.f,0.f};
      if (kk < klim && n < N){
        const float* bp = B + (size_t)(k0+kk)*N + n;
        if (n + 3 < N) v = *(const float4*)bp;
        else { v.x=bp[0]; v.y=(n+1<N)?bp[1]:0.f; v.z=(n+2<N)?bp[2]:0.f; }
      }
      *(float4*)(Bs + kk*68 + nq) = v;
    }
    __syncthreads();
    for (int kk = 0; kk < klim; kk++){
      float4 a = *(const float4*)(As + kk*68 + tm*4);
      float4 bv = *(const float4*)(Bs + kk*68 + tn*4);
      acc[0][0]+=a.x*bv.x; acc[0][1]+=a.x*bv.y; acc[0][2]+=a.x*bv.z; acc[0][3]+=a.x*bv.w;
      acc[1][0]+=a.y*bv.x; acc[1][1]+=a.y*bv.y; acc[1][2]+=a.y*bv.z; acc[1][3]+=a.y*bv.w;
      acc[2][0]+=a.z*bv.x; acc[2][1]+=a.z*bv.y; acc[2][2]+=a.z*bv.z; acc[2][3]+=a.z*bv.w;
      acc[3][0]+=a.w*bv.x; acc[3][1]+=a.w*bv.y; acc[3][2]+=a.w*bv.z; acc[3][3]+=a.w*bv.w;
    }
    __syncthreads();
  }

  #pragma unroll
  for (int i=0;i<4;i++){
    int m = tm*4 + i;
    #pragma unroll
    for (int j=0;j<4;j++){
      int n = nb + tn*4 + j;
      if (n < N){
        if (mode == 0){
          part[((size_t)(ks*64 + m))*N + n] = acc[i][j];
        } else {
          float v = acc[i][j] + (bias ? bias[n] : 0.f);
          if (mode == 2) v = tanhf(v);
          out[(size_t)(mb+m)*N + n] = v;
        }
      }
    }
  }
}

__global__ void reduce64(const float* __restrict__ part, int KS, int MN4, int N,
                         const float* __restrict__ bias, float* __restrict__ out, int mode){
  int idx = blockIdx.x*256 + threadIdx.x;
  if (idx >= MN4) return;
  int base = idx*4;
  int n = base % N;
  float4 s = {0.f,0.f,0.f,0.f};
  size_t stride = (size_t)MN4*4;
  for (int p=0;p<KS;p++){
    float4 t = *(const float4*)(part + (size_t)p*stride + base);
    s.x+=t.x; s.y+=t.y; s.z+=t.z; s.w+=t.w;
  }
  if (bias){
    float4 bb = *(const float4*)(bias + n);
    s.x+=bb.x; s.y+=bb.y; s.z+=bb.z; s.w+=bb.w;
  }
  if (mode == 1){ s.x=tanhf(s.x); s.y=tanhf(s.y); s.z=tanhf(s.z); s.w=tanhf(s.w); }
  *(float4*)(out + base) = s;
}

__global__ __launch_bounds__(256) void comb_kernel(const float* __restrict__ imgf,
                                                   const float* __restrict__ qsum,
                                                   float* __restrict__ comb){
  __shared__ float s_red[4];
  int b = blockIdx.x, tid = threadIdx.x;
  float ss = 0.f;
  for (int j = tid; j < 1024; j += 256){ float v = imgf[b*1024+j]; ss += v*v; }
  ss = wave_sum64(ss);
  if ((tid & 63) == 0) s_red[tid>>6] = ss;
  __syncthreads();
  float inv = 1.0f / sqrtf(s_red[0]+s_red[1]+s_red[2]+s_red[3]);
  for (int j = tid; j < 1024; j += 256)
    comb[b*1024+j] = tanhf(imgf[b*1024+j]*inv * qsum[b*1024+j]*0.05f);
}

__global__ void tanhrvec_kernel(const float* __restrict__ rvecT, float* __restrict__ lastB){
  int idx = blockIdx.x*256 + threadIdx.x;
  if (idx >= 16384) return;
  int b = idx & 63, i = idx >> 6;
  lastB[(size_t)b*1280 + 1024 + i] = tanhf(rvecT[i*64 + b]);
}

// ===================== persistent DNC recurrence kernel ===========================
// Phase I relocated to blocks [I_LO, 256) so D blocks (0..63) skip xi compute.
#define I_LO 138

struct SD_t {
  float s_rk[256], s_rstr[4], s_wkey[64], s_erase[64], s_wvec[64];
  float s_free[4], s_modes[12], s_scal[3], s_pad0[1];   // pad -> s_wr.. 16B-aligned
  float s_wr[1024];
  float s_wwnew[256], s_usage[256], s_prec[256], s_scan[256], s_sim[256];
  float s_C[1024], s_D[1024];
  float s_red[44], s_PQ[8];   // s_red[0..3] legacy; [4..39] fused-reduction scratch
};
struct SGLO_t { float red[4*768]; float g2[768]; };
struct Shm {
  float Wg[768*8];   // 24 KB: [k][8] gate weights (4 gates x 2 cols), persistent
  float Wo[768*4];   // 12 KB: [k][4] out-weight cols, persistent
  float Wi[512*4];   //  8 KB: [k][4] interface-weight cols, persistent
  union { SGLO_t glo; SD_t d; } u;
};

// O-projection for one block's 4 output cols: accO over c=0..11 (same order as
// the original fused GLO loop -> bit-identical). Returns combined value for
// this thread's (b_, col=bid*4+q_); caller applies clip.
__device__ __forceinline__ float glo_opart(const float* __restrict__ rvP,
                                           const float* __restrict__ hP,
                                           const float* __restrict__ WoL,
                                           float* __restrict__ red,
                                           float bo, int lane, int wid, int b_, int q_){
  float accO[4] = {0.f,0.f,0.f,0.f};
  for (int c = 0; c < 12; c++){
    int k0 = c*64 + wid*16;
    bool isH = (k0 >= 256);
    const float* src = isH ? (hP + (size_t)(k0-256)*64) : (rvP + (size_t)k0*64);
    float a[16];
    #pragma unroll
    for (int u=0; u<16; u++) a[u] = src[u*64 + lane];
    #pragma unroll
    for (int u=0; u<16; u++){
      int k = k0 + u;
      int orow = isH ? (k - 256) : (512 + k);
      float4 wo = *(const float4*)(WoL + (size_t)orow*4);
      float av = isH ? clipf_(a[u]) : a[u];
      accO[0] += av*wo.x; accO[1] += av*wo.y; accO[2] += av*wo.z; accO[3] += av*wo.w;
    }
  }
  #pragma unroll
  for (int j=0;j<4;j++) red[wid*256 + j*64 + lane] = accO[j];
  __syncthreads();
  float v = bo;
  #pragma unroll
  for (int w=0;w<4;w++) v += red[w*256 + q_*64 + b_];
  __syncthreads();   // red may be aliased (SD_t) right after
  return v;
}

// barmem layout (1024 ints):
//   subs  [0,256)    stride 16 : gbar group-arrival counters
//   root  @256                 : gbar root counter
//   ggen  [288,544)  stride 16 : gbar per-group release lines (16 spinners each)
//   xict  @576                 : xi completion counter (118 producers, 64 spinners)
//   subsH [608,864)  stride 16 : h completion group-arrival counters
//   rootH @896                 : h completion root (I-block spinners)

__device__ __forceinline__ void gbar(int* subs, int* root, int* ggen, int epoch){
  __syncthreads();   // compiler emits s_waitcnt vmcnt(0) before s_barrier -> all waves drained
  if (threadIdx.x == 0){
    asm volatile("s_waitcnt vmcnt(0)" ::: "memory");
    int g = blockIdx.x & 15;
    int old = __hip_atomic_fetch_add(&subs[g*16], 1, __ATOMIC_RELAXED, __HIP_MEMORY_SCOPE_AGENT);
    if (old == 16*epoch - 1){
      int r = __hip_atomic_fetch_add(root, 1, __ATOMIC_RELAXED, __HIP_MEMORY_SCOPE_AGENT);
      if (r == 16*epoch - 1){
        #pragma unroll
        for (int gg = 0; gg < 16; gg++)
          __hip_atomic_store(&ggen[gg*16], epoch, __ATOMIC_RELAXED, __HIP_MEMORY_SCOPE_AGENT);
      }
    }
    while (__hip_atomic_load(&ggen[g*16], __ATOMIC_RELAXED, __HIP_MEMORY_SCOPE_AGENT) < epoch)
      __builtin_amdgcn_s_sleep(2);
    asm volatile("" ::: "memory");
  }
  __syncthreads();
}

__global__ __launch_bounds__(256) void dnc_recur(
    int T, int outmode, int slot0,
    const float* __restrict__ xpart, const float* __restrict__ Wih_r,
    const float* __restrict__ Whh, const float* __restrict__ gb,
    const float* __restrict__ Wif, const float* __restrict__ bif,
    const float* __restrict__ Wout, const float* __restrict__ bout,
    float* __restrict__ ws, float* __restrict__ outbuf, int* __restrict__ barmem)
{
  __shared__ Shm sh;

  float* memS  = ws + WS_MEM;
  float* linkS = ws + WS_LINK;
  float* precB = ws + WS_PREC;
  float* wrS   = ws + WS_WR;
  float* wwS   = ws + WS_WW;
  float* usgS  = ws + WS_USAGE;
  float* htS   = ws + WS_HTS;
  float* rvS   = ws + WS_RVS;
  float* xiSl  = ws + WS_XIS;
  int* subs  = barmem;
  int* root  = barmem + 256;
  int* ggen  = barmem + 288;
  int* xict  = barmem + 576;
  int* subsH = barmem + 608;
  int* rootH = barmem + 896;

  int tid = threadIdx.x, bid = blockIdx.x;
  int lane = tid & 63, wid = tid >> 6;
  int b_ = tid & 63, q_ = tid >> 6;
  bool isI = (bid >= I_LO);      // xi-producer blocks (118 of them)

  // ---- load persistent weight slices into LDS (once) ----
  {
    int c2 = bid*2;
    float2* Wg2w = (float2*)sh.Wg;
    for (int e2 = tid; e2 < 3072; e2 += 256){
      int k = e2 >> 2, g = e2 & 3;
      const float* src = (k < 256) ? (Wih_r + (size_t)k*2048 + g*512 + c2)
                                   : (Whh + (size_t)(k-256)*2048 + g*512 + c2);
      Wg2w[e2] = *(const float2*)src;
    }
    int c4o = bid*4;
    float4* Wo4 = (float4*)sh.Wo;
    for (int k = tid; k < 768; k += 256)
      Wo4[k] = *(const float4*)(Wout + (size_t)k*1024 + c4o);
    if (isI){
      int c4i = (bid - I_LO)*4;
      for (int e = tid; e < 2048; e += 256){
        int k = e >> 2, c = e & 3;
        int col = c4i + c;
        sh.Wi[e] = (col < 471) ? Wif[(size_t)k*471 + col] : 0.f;
      }
    }
  }
  float bo = bout[bid*4 + q_];
  float bifv = 0.f;
  if (isI && (bid - I_LO)*4 + q_ < 471) bifv = bif[(bid - I_LO)*4 + q_];
  __syncthreads();

  float c_reg = 0.f;   // LSTM cell state (b_, col=bid*2+q_) for tid<128
  float qacc = 0.f;

  for (int t = 0; t < T; t++){
    int pp = t & 1, wp = (t + 1) & 1;
    const float* rvP1 = rvS + (size_t)(slot0+t-1)*16384;   // valid when t>0
    const float* hP1  = htS + (size_t)(slot0+t-1)*32768;

    // ======== phase GLO-gates: gates(t) + LSTM(t) — k-split over 4 waves ========
    {
      if (t > 0){
        float accG[8] = {0.f,0.f,0.f,0.f,0.f,0.f,0.f,0.f};
        for (int c = 0; c < 12; c++){
          int k0 = c*64 + wid*16;                 // wave-owned 16-k slice
          bool isH = (k0 >= 256);
          const float* src = isH ? (hP1 + (size_t)(k0-256)*64) : (rvP1 + (size_t)k0*64);
          float a[16];
          #pragma unroll
          for (int u=0; u<16; u++) a[u] = src[u*64 + lane];   // coalesced L2 reads
          #pragma unroll
          for (int u=0; u<16; u++){
            int k = k0 + u;
            float4 w0 = *(const float4*)(sh.Wg + (size_t)k*8);       // broadcast
            float4 w1 = *(const float4*)(sh.Wg + (size_t)k*8 + 4);   // broadcast
            float av = a[u];
            accG[0] += av*w0.x; accG[1] += av*w0.y; accG[2] += av*w0.z; accG[3] += av*w0.w;
            accG[4] += av*w1.x; accG[5] += av*w1.y; accG[6] += av*w1.z; accG[7] += av*w1.w;
          }
        }
        #pragma unroll
        for (int j=0;j<8;j++) sh.u.glo.red[wid*768 + j*64 + lane] = accG[j];
      }
      __syncthreads();
      // combine: thread (b_,q_) handles j = q_, q_+4
      #pragma unroll
      for (int v=0; v<2; v++){
        int j = q_ + v*4;
        int col = (j>>1)*512 + bid*2 + (j&1);
        float s = gb[col] + xpart[((size_t)(t*64 + b_))*2048 + col];
        if (t > 0){
          s += sh.u.glo.red[0*768 + j*64 + b_];
          s += sh.u.glo.red[1*768 + j*64 + b_];
          s += sh.u.glo.red[2*768 + j*64 + b_];
          s += sh.u.glo.red[3*768 + j*64 + b_];
        }
        sh.u.glo.g2[j*64 + b_] = s;
      }
      __syncthreads();
      if (tid < 128){
        int jj = q_;
        float gi = sh.u.glo.g2[(0+jj)*64 + b_];
        float gf = sh.u.glo.g2[(2+jj)*64 + b_];
        float gg = sh.u.glo.g2[(4+jj)*64 + b_];
        float go = sh.u.glo.g2[(6+jj)*64 + b_];
        float cn = sigmoidf_(gf)*c_reg + sigmoidf_(gi)*tanhf(gg);
        float hn = sigmoidf_(go)*tanhf(cn);
        c_reg = cn;
        int col = bid*2 + jj;
        cstore(&htS[(size_t)(slot0+t)*32768 + col*64 + b_], hn);
      }
    }

    // -- signal h(t) complete: hierarchical arrival, no release broadcast --
    __syncthreads();   // drains all waves' h cstores (vmcnt(0) before s_barrier)
    if (tid == 0){
      asm volatile("s_waitcnt vmcnt(0)" ::: "memory");
      int g = bid & 15;
      int old = __hip_atomic_fetch_add(&subsH[g*16], 1, __ATOMIC_RELAXED, __HIP_MEMORY_SCOPE_AGENT);
      if (old == 16*(t+1) - 1)
        __hip_atomic_fetch_add(rootH, 1, __ATOMIC_RELAXED, __HIP_MEMORY_SCOPE_AGENT);
    }

    // ======== O(t-1) for D + middle blocks (overlaps phase I on I-blocks) ========
    if (!isI && t > 0){
      float v = glo_opart(rvP1, hP1, sh.Wo, sh.u.glo.red, bo, lane, wid, b_, q_);
      qacc += clipf_(v);
    }

    // ======== phase I (blocks I_LO..255): wait h(t), xi = clip(h) @ Wif + bif ========
    if (isI){
      if (tid == 0){
        while (__hip_atomic_load(rootH, __ATOMIC_RELAXED, __HIP_MEMORY_SCOPE_AGENT) < 16*(t+1))
          __builtin_amdgcn_s_sleep(1);
        asm volatile("" ::: "memory");
      }
      __syncthreads();
      float acc[4] = {0.f,0.f,0.f,0.f};
      const float* hP = htS + (size_t)(slot0+t)*32768;
      for (int c = 0; c < 8; c++){
        int k0 = c*64 + wid*16;
        float a[16];
        #pragma unroll
        for (int u=0; u<16; u++) a[u] = hP[(size_t)(k0+u)*64 + lane];
        #pragma unroll
        for (int u=0; u<16; u++){
          float4 wv = *(const float4*)(sh.Wi + (size_t)(k0+u)*4);   // broadcast
          float ac = clipf_(a[u]);
          acc[0] += ac*wv.x; acc[1] += ac*wv.y; acc[2] += ac*wv.z; acc[3] += ac*wv.w;
        }
      }
      #pragma unroll
      for (int j=0;j<4;j++) sh.u.glo.red[wid*256 + j*64 + lane] = acc[j];
      __syncthreads();
      {
        float s = bifv;
        #pragma unroll
        for (int w=0;w<4;w++) s += sh.u.glo.red[w*256 + q_*64 + b_];
        int col = (bid - I_LO)*4 + q_;
        if (col < 471) cstore(&xiSl[(size_t)(slot0+t)*30144 + b_*471 + col], s);
      }
      // signal xi complete (stores drained by the barrier below)
      __syncthreads();
      if (tid == 0)
        __hip_atomic_fetch_add(xict, 1, __ATOMIC_RELAXED, __HIP_MEMORY_SCOPE_AGENT);
      // deferred O(t-1) — fills idle window while phase D runs
      if (t > 0){
        float v = glo_opart(rvP1, hP1, sh.Wo, sh.u.glo.red, bo, lane, wid, b_, q_);
        qacc += clipf_(v);
      }
    }

    // ======== phase D: DNC memory step (blocks 0..63) ========
    if (bid < 64){
      SD_t& sd = sh.u.d;
      int b = bid;
      const float* prec_in  = precB + pp*16384;
      float*       prec_out = precB + wp*16384;

      // ---- Stage 1a: preload private state (independent of xi) ----
      for (int e = tid; e < 1024; e += 256){
        sd.s_wr[e] = wrS[(size_t)b*1024 + e];
        sd.s_C[e] = 0.f; sd.s_D[e] = 0.f;
      }
      float wwold = wwS[(size_t)b*256 + tid];
      sd.s_usage[tid] = usgS[(size_t)b*256 + tid];
      sd.s_prec[tid]  = prec_in[(size_t)b*256 + tid];

      // ---- wait for xi(t) (overlapped with preloads above) ----
      if (tid == 0){
        while (__hip_atomic_load(xict, __ATOMIC_RELAXED, __HIP_MEMORY_SCOPE_AGENT) < 118*(t+1))
          __builtin_amdgcn_s_sleep(1);
        asm volatile("" ::: "memory");
      }
      __syncthreads();

      // ---- Stage 1b: parse interface vector ----
      const float* xrow = xiSl + (size_t)(slot0+t)*30144 + (size_t)b*471;
      for (int idx = tid; idx < 471; idx += 256){
        float v = xrow[idx];
        if (idx < 256)       sd.s_rk[idx] = tanhf(v);
        else if (idx < 260)  sd.s_rstr[idx-256] = softplusf_(v);
        else if (idx < 324)  sd.s_wkey[idx-260] = v;
        else if (idx == 324) sd.s_scal[0] = softplusf_(v);
        else if (idx < 389)  sd.s_erase[idx-325] = sigmoidf_(v);
        else if (idx < 453)  sd.s_wvec[idx-389] = tanhf(v);
        else if (idx < 457)  sd.s_free[idx-453] = sigmoidf_(v);
        else if (idx == 457) sd.s_scal[1] = sigmoidf_(v);
        else if (idx == 458) sd.s_scal[2] = sigmoidf_(v);
        else                 sd.s_modes[idx-459] = v;
      }
      __syncthreads();

      if (tid < 4){
        float m0 = sd.s_modes[tid*3], m1 = sd.s_modes[tid*3+1], m2 = sd.s_modes[tid*3+2];
        float mx = fmaxf(m0, fmaxf(m1,m2));
        float e0 = expf(m0-mx), e1 = expf(m1-mx), e2 = expf(m2-mx);
        float s = e0+e1+e2;
        sd.s_modes[tid*3] = e0/s; sd.s_modes[tid*3+1] = e1/s; sd.s_modes[tid*3+2] = e2/s;
      }
      {
        float k = sd.s_rk[wid*64 + lane];
        float ss = wave_sum64(k*k);
        sd.s_rk[wid*64 + lane] = k / (sqrtf(ss) + EPSV);
      }
      if (wid == 0){
        float k = sd.s_wkey[lane];
        float ss = wave_sum64(k*k);
        sd.s_wkey[lane] = k / (sqrtf(ss) + EPSV);
      }

      // ---- Stage 2: usage update ----
      {
        float psi = 1.f;
        #pragma unroll
        for (int r=0;r<4;r++) psi *= (1.f - sd.s_free[r]*sd.s_wr[r*256+tid]);
        float u = (sd.s_usage[tid] + wwold - sd.s_usage[tid]*wwold) * psi;
        sd.s_usage[tid] = u;
        usgS[(size_t)b*256 + tid] = u;
      }
      __syncthreads();

      // ---- Stage 3: stable ascending rank (float4 reads) ----
      int rank_r;
      {
        float u = sd.s_usage[tid];
        int rank = 0;
        #pragma unroll 4
        for (int j4=0;j4<256;j4+=4){
          float4 uv = *(const float4*)(sd.s_usage + j4);
          rank += (uv.x < u) || (uv.x == u && (j4+0) < tid);
          rank += (uv.y < u) || (uv.y == u && (j4+1) < tid);
          rank += (uv.z < u) || (uv.z == u && (j4+2) < tid);
          rank += (uv.w < u) || (uv.w == u && (j4+3) < tid);
        }
        rank_r = rank;
        sd.s_scan[rank] = u;
      }
      __syncthreads();

      // ---- Stage 4: inclusive product scan — wave shfl scan + wave-prefix ----
      {
        float v = sd.s_scan[tid];
        #pragma unroll
        for (int off=1; off<64; off<<=1){
          float u2 = __shfl_up(v, off, 64);
          if (lane >= off) v *= u2;
        }
        if (lane == 63) sd.s_red[wid] = v;     // wave total
        __syncthreads();
        float pre = 1.f;
        if (wid > 0) pre *= sd.s_red[0];
        if (wid > 1) pre *= sd.s_red[1];
        if (wid > 2) pre *= sd.s_red[2];
        v *= pre;
        sd.s_scan[tid] = v;
        __syncthreads();
      }
      float alloc_r;
      {
        float u = sd.s_usage[tid];
        float cpe = (rank_r > 0) ? sd.s_scan[rank_r-1] : 1.f;
        alloc_r = (1.f - u) * cpe;
      }

      // ---- Stage 5: write-key cosine (row-per-thread) ----
      {
        const float4* Mrow = (const float4*)(memS + (size_t)b*16384 + (size_t)tid*64);
        float nrm2 = 0.f, dt = 0.f;
        #pragma unroll
        for (int c4 = 0; c4 < 16; c4++){
          float4 mv = Mrow[c4];
          int w0 = c4*4;
          nrm2 += mv.x*mv.x + mv.y*mv.y + mv.z*mv.z + mv.w*mv.w;
          dt += mv.x*sd.s_wkey[w0] + mv.y*sd.s_wkey[w0+1] + mv.z*sd.s_wkey[w0+2] + mv.w*sd.s_wkey[w0+3];
        }
        sd.s_sim[tid] = dt / (sqrtf(nrm2)+EPSV) * sd.s_scal[0];
      }
      __syncthreads();

      // ---- Stage 6: write softmax, ww, prec, P, Q (fused 9-sum, results -> LDS) ----
      {
        float v = sd.s_sim[tid];
        float mx = block_max256(v, sd.s_red);
        float e = expf(v - mx);
        float sm = block_sum256(e, sd.s_red);
        float cw = e / sm;
        float wwn = sd.s_scal[2] * (sd.s_scal[1]*alloc_r + (1.f - sd.s_scal[1])*cw);
        sd.s_wwnew[tid] = wwn;
        wwS[(size_t)b*256 + tid] = wwn;
        float r9[9];
        r9[0] = wwn;
        #pragma unroll
        for (int r=0;r<4;r++) r9[1+r] = sd.s_prec[tid]*sd.s_wr[r*256+tid];
        #pragma unroll
        for (int r=0;r<4;r++) r9[5+r] = wwn*sd.s_wr[r*256+tid];
        block_sumN<9>(r9, sd.s_red + 4);
        prec_out[(size_t)b*256 + tid] = (1.f - r9[0])*sd.s_prec[tid] + wwn;
        if (tid == 0){
          #pragma unroll
          for (int r=0;r<4;r++){ sd.s_PQ[r] = r9[1+r]; sd.s_PQ[4+r] = r9[5+r]; }
        }
      }
      __syncthreads();

      // ---- Stage 8a: A,B row-sums vs OLD link ----
      float aA[4] = {0,0,0,0}, aB[4] = {0,0,0,0};
      {
        const float4* Lrow = (const float4*)(linkS + (size_t)b*65536 + (size_t)tid*256);
        for (int c4 = 0; c4 < 64; c4++){
          float4 lv = Lrow[c4];
          int j = c4*4;
          float w0n = sd.s_wwnew[j], w1n = sd.s_wwnew[j+1], w2n = sd.s_wwnew[j+2], w3n = sd.s_wwnew[j+3];
          #pragma unroll
          for (int r=0;r<4;r++){
            float wr0 = sd.s_wr[r*256+j], wr1 = sd.s_wr[r*256+j+1];
            float wr2 = sd.s_wr[r*256+j+2], wr3 = sd.s_wr[r*256+j+3];
            aA[r] += lv.x*wr0 + lv.y*wr1 + lv.z*wr2 + lv.w*wr3;
            aB[r] += lv.x*(w0n*wr0) + lv.y*(w1n*wr1) + lv.z*(w2n*wr2) + lv.w*(w3n*wr3);
          }
        }
      }
      __syncthreads();

      // ---- Stage 8b: link update + C,D col-sums ----
      {
        int cg = tid & 63, ioff = tid >> 6;
        int j0 = cg*4;
        float wwj0 = sd.s_wwnew[j0], wwj1 = sd.s_wwnew[j0+1], wwj2 = sd.s_wwnew[j0+2], wwj3 = sd.s_wwnew[j0+3];
        float pj0 = sd.s_prec[j0], pj1 = sd.s_prec[j0+1], pj2 = sd.s_prec[j0+2], pj3 = sd.s_prec[j0+3];
        float cC[4][4] = {{0}}, cD[4][4] = {{0}};
        float4* Lb = (float4*)(linkS + (size_t)b*65536);
        for (int it = 0; it < 64; it++){
          int i = it*4 + ioff;
          float4 lv = Lb[(size_t)i*64 + cg];
          float wwi = sd.s_wwnew[i];
          float4 ln;
          ln.x = (1.f - wwi - wwj0)*lv.x + wwi*pj0;
          ln.y = (1.f - wwi - wwj1)*lv.y + wwi*pj1;
          ln.z = (1.f - wwi - wwj2)*lv.z + wwi*pj2;
          ln.w = (1.f - wwi - wwj3)*lv.w + wwi*pj3;
          if (i >= j0 && i < j0+4){
            if (i == j0)        ln.x = 0.f;
            else if (i == j0+1) ln.y = 0.f;
            else if (i == j0+2) ln.z = 0.f;
            else                ln.w = 0.f;
          }
          Lb[(size_t)i*64 + cg] = ln;
          #pragma unroll
          for (int r=0;r<4;r++){
            float wri = sd.s_wr[r*256+i];
            float vbi = wwi*wri;
            cC[r][0] += lv.x*wri; cC[r][1] += lv.y*wri; cC[r][2] += lv.z*wri; cC[r][3] += lv.w*wri;
            cD[r][0] += lv.x*vbi; cD[r][1] += lv.y*vbi; cD[r][2] += lv.z*vbi; cD[r][3] += lv.w*vbi;
          }
        }
        for (int w=0; w<4; w++){
          if (ioff == w){
            #pragma unroll
            for (int r=0;r<4;r++){
              sd.s_C[r*256+j0+0] += cC[r][0]; sd.s_C[r*256+j0+1] += cC[r][1];
              sd.s_C[r*256+j0+2] += cC[r][2]; sd.s_C[r*256+j0+3] += cC[r][3];
              sd.s_D[r*256+j0+0] += cD[r][0]; sd.s_D[r*256+j0+1] += cD[r][1];
              sd.s_D[r*256+j0+2] += cD[r][2]; sd.s_D[r*256+j0+3] += cD[r][3];
            }
          }
          __syncthreads();
        }
      }

      // ---- Stage 7+9 merged: mem RMW + read-key dots ----
      float pr[4];
      {
        float4* Mrow = (float4*)(memS + (size_t)b*16384 + (size_t)tid*64);
        float wwn = sd.s_wwnew[tid];
        float nrm2 = 0.f, d0=0.f, d1=0.f, d2=0.f, d3=0.f;
        #pragma unroll
        for (int c4 = 0; c4 < 16; c4++){
          float4 mv = Mrow[c4];
          int w0 = c4*4;
          mv.x = mv.x*(1.f - wwn*sd.s_erase[w0+0]) + wwn*sd.s_wvec[w0+0];
          mv.y = mv.y*(1.f - wwn*sd.s_erase[w0+1]) + wwn*sd.s_wvec[w0+1];
          mv.z = mv.z*(1.f - wwn*sd.s_erase[w0+2]) + wwn*sd.s_wvec[w0+2];
          mv.w = mv.w*(1.f - wwn*sd.s_erase[w0+3]) + wwn*sd.s_wvec[w0+3];
          Mrow[c4] = mv;
          nrm2 += mv.x*mv.x + mv.y*mv.y + mv.z*mv.z + mv.w*mv.w;
          d0 += mv.x*sd.s_rk[w0] + mv.y*sd.s_rk[w0+1] + mv.z*sd.s_rk[w0+2] + mv.w*sd.s_rk[w0+3];
          d1 += mv.x*sd.s_rk[64+w0] + mv.y*sd.s_rk[64+w0+1] + mv.z*sd.s_rk[64+w0+2] + mv.w*sd.s_rk[64+w0+3];
          d2 += mv.x*sd.s_rk[128+w0] + mv.y*sd.s_rk[128+w0+1] + mv.z*sd.s_rk[128+w0+2] + mv.w*sd.s_rk[128+w0+3];
          d3 += mv.x*sd.s_rk[192+w0] + mv.y*sd.s_rk[192+w0+1] + mv.z*sd.s_rk[192+w0+2] + mv.w*sd.s_rk[192+w0+3];
        }
        float inv = 1.f/(sqrtf(nrm2)+EPSV);
        pr[0] = d0*inv*sd.s_rstr[0];
        pr[1] = d1*inv*sd.s_rstr[1];
        pr[2] = d2*inv*sd.s_rstr[2];
        pr[3] = d3*inv*sd.s_rstr[3];
      }
      // ---- read softmax: fused 4-max + 4-sum ----
      {
        float m4[4] = {pr[0], pr[1], pr[2], pr[3]};
        block_maxN<4>(m4, sd.s_red + 4);
        float e4[4];
        #pragma unroll
        for (int r=0;r<4;r++) e4[r] = expf(pr[r] - m4[r]);
        float s4[4] = {e4[0], e4[1], e4[2], e4[3]};
        block_sumN<4>(s4, sd.s_red + 4);
        #pragma unroll
        for (int r=0;r<4;r++) pr[r] = e4[r]/s4[r];
      }
      __syncthreads();

      // ---- Stage 10: fw/bw assembly + wr update ----
      {
        float wwn = sd.s_wwnew[tid], pn = sd.s_prec[tid];
        #pragma unroll
        for (int r=0;r<4;r++){
          float wro = sd.s_wr[r*256+tid];
          float fw  = (1.f-wwn)*aA[r] - aB[r] + wwn*(sd.s_PQ[r] - pn*wro);
          float bwv = (1.f-wwn)*sd.s_C[r*256+tid] - sd.s_D[r*256+tid] + pn*(sd.s_PQ[4+r] - wwn*wro);
          float wrn = sd.s_modes[r*3+0]*bwv + sd.s_modes[r*3+1]*pr[r] + sd.s_modes[r*3+2]*fw;
          wrS[(size_t)b*1024 + r*256 + tid] = wrn;
          sd.s_wr[r*256+tid] = wrn;
        }
      }
      __syncthreads();

      // ---- Stage 11: rvecT slot = (wr_new @ mem)^T ----
      {
        int r = tid >> 6, w = tid & 63;
        const float* Mb = memS + (size_t)b*16384;
        float acc = 0.f;
        for (int n=0; n<256; n++) acc += sd.s_wr[r*256+n]*Mb[(size_t)n*64 + w];
        cstore(&rvS[(size_t)(slot0+t)*16384 + (r*64 + w)*64 + b], acc);
      }
    }

    // single full barrier per step: orders rvec(t) (and transitively h(t), xi(t))
    gbar(subs, root, ggen, t+1);
  }

  // ======== final O(T-1) ========
  {
    float v = glo_opart(rvS + (size_t)(slot0+T-1)*16384,
                        htS + (size_t)(slot0+T-1)*32768,
                        sh.Wo, sh.u.glo.red, bo, lane, wid, b_, q_);
    v = clipf_(v);
    if (outmode == 0){
      qacc += v;
      outbuf[(size_t)b_*1024 + (bid*4 + q_)] = qacc;
    } else {
      outbuf[(size_t)b_*1280 + (bid*4 + q_)] = tanhf(v);
    }
  }
}

// ======================================================================================
extern "C" void kernel_launch(void* const* d_in, const int* in_sizes, int n_in,
                              void* d_out, int out_size, void* d_ws, size_t ws_size,
                              hipStream_t stream) {
  const float* img_feat = (const float*)d_in[0];
  const int*   qst      = (const int*)  d_in[1];
  const float* emb      = (const float*)d_in[2];
  const float* img_W    = (const float*)d_in[3];
  const float* img_b    = (const float*)d_in[4];
  const float* q_Wih    = (const float*)d_in[5];
  const float* q_Whh    = (const float*)d_in[6];
  const float* q_b      = (const float*)d_in[7];
  const float* q_Wif    = (const float*)d_in[8];
  const float* q_bif    = (const float*)d_in[9];
  const float* q_Wout   = (const float*)d_in[10];
  const float* q_bout   = (const float*)d_in[11];
  const float* c_Wih    = (const float*)d_in[12];
  const float* c_Whh    = (const float*)d_in[13];
  const float* c_b      = (const float*)d_in[14];
  const float* c_Wif    = (const float*)d_in[15];
  const float* c_bif    = (const float*)d_in[16];
  const float* c_Wout   = (const float*)d_in[17];
  const float* c_bout   = (const float*)d_in[18];
  const float* fc1_W    = (const float*)d_in[19];
  const float* fc1_b    = (const float*)d_in[20];
  const float* fc2_W    = (const float*)d_in[21];
  const float* fc2_b    = (const float*)d_in[22];

  float* ws = (float*)d_ws;
  float* qv    = ws + WS_QV;
  float* gxp   = ws + WS_GXP;
  float* zoneC = ws + WS_ZONEC;
  float* imgf  = ws + WS_IMGF;
  float* combB = ws + WS_COMB;
  float* lastB = ws + WS_LASTB;
  float* hid1  = ws + WS_HID1;
  float* qsum  = ws + WS_QSUM;
  int*   bar   = (int*)(ws + WS_BAR);

  // zero state zone (mem/link/prec/wr/ww/usage/bar)
  hipMemsetAsync(ws, 0, (size_t)WS_ZONEA*4, stream);

  // qv[(t*64+b)][300] = tanh(emb[qst])
  embed_kernel<<<1500, 256, 0, stream>>>(qst, emb, qv);

  // image fc: imgf = img_feat @ img_W + img_b  (split-K 16)
  gemm64<<<dim3(16,16,1), 256, 0, stream>>>(64, 1024, 4096, 16,
      img_feat, 4096, img_W, nullptr, nullptr, zoneC, 0);
  reduce64<<<64, 256, 0, stream>>>(zoneC, 16, 16384, 1024, img_b, imgf, 0);

  // gxp = qv @ q_Wih[0:300]
  gemm64<<<dim3(32,1,20), 256, 0, stream>>>(1280, 2048, 300, 1,
      qv, 300, q_Wih, nullptr, gxp, nullptr, 1);

  // question DNC, 20 steps (persistent), slots 0..19
  dnc_recur<<<256, 256, 0, stream>>>(20, 0, 0,
      gxp, q_Wih + (size_t)300*2048, q_Whh, q_b,
      q_Wif, q_bif, q_Wout, q_bout, ws, qsum, bar);

  // comb = tanh(l2norm(imgf) * qsum/20)
  comb_kernel<<<64, 256, 0, stream>>>(imgf, qsum, combB);

  // reset state zone for controller
  hipMemsetAsync(ws, 0, (size_t)WS_ZONEA*4, stream);

  // cxp = comb @ c_Wih[0:1024]  (split-K 4)
  gemm64<<<dim3(32,4,1), 256, 0, stream>>>(64, 2048, 1024, 4,
      combB, 1024, c_Wih, nullptr, nullptr, zoneC, 0);
  reduce64<<<128, 256, 0, stream>>>(zoneC, 4, 32768, 2048, nullptr, gxp, 0);

  // controller DNC, 1 step (persistent), slot 20 -> lastB[:, :1024]
  dnc_recur<<<256, 256, 0, stream>>>(1, 1, 20,
      gxp, c_Wih + (size_t)1024*2048, c_Whh, c_b,
      c_Wif, c_bif, c_Wout, c_bout, ws, lastB, bar);

  // lastB[:, 1024:1280] = tanh(rvec_ctrl)  (rvec slot 20)
  tanhrvec_kernel<<<64, 256, 0, stream>>>(ws + WS_RVS + (size_t)20*16384, lastB);

  // fc1: hid1 = tanh(lastB @ fc1_W + fc1_b)  (split-K 5)
  gemm64<<<dim3(47,5,1), 256, 0, stream>>>(64, 3000, 1280, 5,
      lastB, 1280, fc1_W, nullptr, nullptr, zoneC, 0);
  reduce64<<<188, 256, 0, stream>>>(zoneC, 5, 48000, 3000, fc1_b, hid1, 1);

  // fc2: logits = hid1 @ fc2_W + fc2_b  (split-K 6)
  gemm64<<<dim3(47,6,1), 256, 0, stream>>>(64, 3000, 3000, 6,
      hid1, 3000, fc2_W, nullptr, nullptr, zoneC, 0);
  reduce64<<<188, 256, 0, stream>>>(zoneC, 6, 48000, 3000, fc2_b, (float*)d_out, 0);
}